// Round 18
// baseline (363.971 us; speedup 1.0000x reference)
//
#include <hip/hip_runtime.h>
#include <hip/hip_bf16.h>
#include <cstdint>

#define M_ROWS 16384

typedef __attribute__((ext_vector_type(8))) short short8;
typedef __attribute__((ext_vector_type(4))) float f32x4;

__device__ __forceinline__ unsigned long long umin64(unsigned long long a,
                                                     unsigned long long b) {
  return a < b ? a : b;
}

// ---------------------------------------------------------------------------
// PROLOGUE: 8 weight transposes + SA1 fused MLP in one dispatch.
// ---------------------------------------------------------------------------
struct TJobs {
  const float* W[8];
  __hip_bfloat16* Wt[8];
  int K[8], N[8], bx[8], off[8];
};

__global__ __launch_bounds__(256) void prologue_kernel(
    TJobs jb, int toff,
    const float* __restrict__ x,
    const float* __restrict__ w0,
    const float* __restrict__ b0,
    const float* __restrict__ w1,
    const float* __restrict__ b1,
    float* __restrict__ G1)
{
  __shared__ float tile[32][33];
  __shared__ __align__(16) float Ts[64][68];
  __shared__ __align__(16) float Ws[64][68];
  __shared__ float xs[64][2];
  __shared__ float w0s[2][64];
  __shared__ float b0s[64];
  int bid = blockIdx.x;
  int tid = threadIdx.x;
  if (bid < toff) {
    int j = 0;
#pragma unroll
    for (int t = 1; t < 8; t++)
      if (bid >= jb.off[t]) j = t;
    int rel = bid - jb.off[j];
    int K = jb.K[j], N = jb.N[j];
    const float* W = jb.W[j];
    __hip_bfloat16* Wt = jb.Wt[j];
    int n0 = (rel % jb.bx[j]) << 5, k0 = (rel / jb.bx[j]) << 5;
    int c = tid & 31, i0 = tid >> 5;
#pragma unroll
    for (int p = 0; p < 4; p++) {
      int i = i0 + p * 8;
      tile[i][c] = W[(size_t)(k0 + i) * N + n0 + c];
    }
    __syncthreads();
#pragma unroll
    for (int p = 0; p < 4; p++) {
      int r = i0 + p * 8;
      Wt[(size_t)(n0 + r) * K + k0 + c] = (__hip_bfloat16)tile[c][r];
    }
    return;
  }
  int m0 = (bid - toff) << 6;
  if (tid < 128) {
    ((float*)xs)[tid] = x[(size_t)m0 * 2 + tid];
  } else if (tid < 192) {
    int n = tid - 128;
    w0s[0][n] = w0[n];
    b0s[n] = b0[n];
  } else {
    int n = tid - 192;
    w0s[1][n] = w0[64 + n];
  }
#pragma unroll
  for (int i = 0; i < 16; i++) {
    int idx = tid + (i << 8);
    int k = idx >> 6, n = idx & 63;
    Ws[k][n] = w1[(size_t)k * 64 + n];
  }
  __syncthreads();
#pragma unroll
  for (int i = 0; i < 16; i++) {
    int idx = tid + (i << 8);
    int m = idx >> 6, n = idx & 63;
    float acc = 0.f;
    acc += xs[m][0] * w0s[0][n];
    acc += xs[m][1] * w0s[1][n];
    Ts[n][m] = fmaxf(acc + b0s[n], 0.f);
  }
  __syncthreads();
  int tx = tid & 15, ty = tid >> 4;
  float acc[4][4] = {};
  for (int k = 0; k < 64; k++) {
    float4 a4 = *(const float4*)&Ts[k][ty << 2];
    float4 b4 = *(const float4*)&Ws[k][tx << 2];
    float av[4] = {a4.x, a4.y, a4.z, a4.w};
    float bv[4] = {b4.x, b4.y, b4.z, b4.w};
#pragma unroll
    for (int i = 0; i < 4; i++)
#pragma unroll
      for (int j = 0; j < 4; j++)
        acc[i][j] += av[i] * bv[j];
  }
  float4 bb = *(const float4*)&b1[tx << 2];
  float bv[4] = {bb.x, bb.y, bb.z, bb.w};
#pragma unroll
  for (int i = 0; i < 4; i++) {
    int m = m0 + (ty << 2) + i;
    float4 o;
    o.x = fmaxf(acc[i][0] + bv[0], 0.f);
    o.y = fmaxf(acc[i][1] + bv[1], 0.f);
    o.z = fmaxf(acc[i][2] + bv[2], 0.f);
    o.w = fmaxf(acc[i][3] + bv[3], 0.f);
    *(float4*)&G1[(size_t)m * 64 + (tx << 2)] = o;
  }
}

// ---------------------------------------------------------------------------
// SA2 body (bit-identical H2; LDS 47616 B laid out in smem).
// ---------------------------------------------------------------------------
__device__ void sa2_body(char* smem,
    const float* __restrict__ X1,
    const float* __restrict__ w0,
    const float* __restrict__ b0,
    const float* __restrict__ w1,
    const float* __restrict__ b1,
    float* __restrict__ H2, int m0)
{
  float (*Ts)[68] = (float(*)[68])smem;                    // 128x68 f
  float (*Bs)[132] = (float(*)[132])(smem + 34816);        // 16x132 f
  float (*Xs)[68] = (float(*)[68])(smem + 43264);          // 16x68 f
  int tid = threadIdx.x;
  int tx = tid & 15, ty = tid >> 4;
  float acc1[4][8] = {};
  for (int k0 = 0; k0 < 64; k0 += 16) {
#pragma unroll
    for (int i = 0; i < 4; i++) {
      int idx = tid + (i << 8);
      int m = idx >> 4, k = idx & 15;
      Xs[k][m] = X1[(size_t)(m0 + m) * 64 + k0 + k];
    }
#pragma unroll
    for (int i = 0; i < 8; i++) {
      int idx = tid + (i << 8);
      int n = idx & 127, k = idx >> 7;
      Bs[k][n] = w0[(size_t)(k0 + k) * 128 + n];
    }
    __syncthreads();
#pragma unroll
    for (int k = 0; k < 16; k++) {
      float av[4], bv[8];
#pragma unroll
      for (int i = 0; i < 4; i++) av[i] = Xs[k][ty * 4 + i];
#pragma unroll
      for (int j = 0; j < 8; j++) bv[j] = Bs[k][tx * 8 + j];
#pragma unroll
      for (int i = 0; i < 4; i++)
#pragma unroll
        for (int j = 0; j < 8; j++)
          acc1[i][j] += av[i] * bv[j];
    }
    __syncthreads();
  }
#pragma unroll
  for (int j = 0; j < 8; j++) {
    float bbv = b0[tx * 8 + j];
#pragma unroll
    for (int i = 0; i < 4; i++)
      Ts[tx * 8 + j][ty * 4 + i] = fmaxf(acc1[i][j] + bbv, 0.f);
  }
  __syncthreads();
  float acc2[4][8] = {};
  for (int k0 = 0; k0 < 128; k0 += 16) {
#pragma unroll
    for (int i = 0; i < 8; i++) {
      int idx = tid + (i << 8);
      int n = idx & 127, k = idx >> 7;
      Bs[k][n] = w1[(size_t)(k0 + k) * 128 + n];
    }
    __syncthreads();
#pragma unroll
    for (int k = 0; k < 16; k++) {
      float av[4], bv[8];
#pragma unroll
      for (int i = 0; i < 4; i++) av[i] = Ts[k0 + k][ty * 4 + i];
#pragma unroll
      for (int j = 0; j < 8; j++) bv[j] = Bs[k][tx * 8 + j];
#pragma unroll
      for (int i = 0; i < 4; i++)
#pragma unroll
        for (int j = 0; j < 8; j++)
          acc2[i][j] += av[i] * bv[j];
    }
    __syncthreads();
  }
#pragma unroll
  for (int i = 0; i < 4; i++) {
    int m = m0 + ty * 4 + i;
#pragma unroll
    for (int j = 0; j < 8; j++) {
      int n = tx * 8 + j;
      H2[(size_t)m * 128 + n] = fmaxf(acc2[i][j] + b1[n], 0.f);
    }
  }
}

// ---------------------------------------------------------------------------
// Ball-mask body (split-bf16 MFMA gram + exact guard band; bit-identical).
// LDS layout in smem: Qh 0, Ql 10240, Ch 20480, Cl 30720, tw 40960,
// nqs 43008, ncs 43520 (total 44032 B).
// ---------------------------------------------------------------------------
template <int C>
__device__ void ball_body(char* smem,
    const float* __restrict__ F32,
    const __hip_bfloat16* __restrict__ Fhi,
    const __hip_bfloat16* __restrict__ Flo,
    const float* __restrict__ nrm,
    unsigned long long* __restrict__ mask,
    float r2, int pairIdx, int batch)
{
  short (*Qh)[40] = (short(*)[40])smem;
  short (*Ql)[40] = (short(*)[40])(smem + 10240);
  short (*Ch)[40] = (short(*)[40])(smem + 20480);
  short (*Cl)[40] = (short(*)[40])(smem + 30720);
  unsigned int (*tw)[4] = (unsigned int(*)[4])(smem + 40960);
  float* nqs = (float*)(smem + 43008);
  float* ncs = (float*)(smem + 43520);
  int tid = threadIdx.x;
  int p = pairIdx;
  int qt = 0;
  while (p >= 16 - qt) { p -= 16 - qt; qt++; }
  int ct = qt + p;
  int b0 = batch << 11;
  int q0 = b0 + (qt << 7), c0 = b0 + (ct << 7);
  tw[tid >> 1][(tid & 1) * 2] = 0;
  tw[tid >> 1][(tid & 1) * 2 + 1] = 0;
  if (tid < 128) nqs[tid] = nrm[q0 + tid];
  else ncs[tid - 128] = nrm[c0 + tid - 128];

  int wave = tid >> 6, lane = tid & 63;
  int quad = lane >> 4, l16 = lane & 15;
  int wm = (wave >> 1) << 6, wn = (wave & 1) << 6;
  f32x4 acc[4][4] = {};
  const short* QH = (const short*)Fhi;
  const short* QL = (const short*)Flo;
  int srow = tid >> 2, sq = tid & 3;
  for (int k0 = 0; k0 < C; k0 += 32) {
#pragma unroll
    for (int h = 0; h < 2; h++) {
      int r = srow + (h << 6);
      *(uint4*)&Qh[r][sq * 8] = *(const uint4*)&QH[(size_t)(q0 + r) * C + k0 + sq * 8];
      *(uint4*)&Ql[r][sq * 8] = *(const uint4*)&QL[(size_t)(q0 + r) * C + k0 + sq * 8];
      *(uint4*)&Ch[r][sq * 8] = *(const uint4*)&QH[(size_t)(c0 + r) * C + k0 + sq * 8];
      *(uint4*)&Cl[r][sq * 8] = *(const uint4*)&QL[(size_t)(c0 + r) * C + k0 + sq * 8];
    }
    __syncthreads();
    short8 ah[4], al[4];
#pragma unroll
    for (int mi = 0; mi < 4; mi++) {
      ah[mi] = *(const short8*)&Qh[wm + mi * 16 + l16][quad * 8];
      al[mi] = *(const short8*)&Ql[wm + mi * 16 + l16][quad * 8];
    }
#pragma unroll
    for (int ni = 0; ni < 4; ni++) {
      short8 bh = *(const short8*)&Ch[wn + ni * 16 + l16][quad * 8];
      short8 bl = *(const short8*)&Cl[wn + ni * 16 + l16][quad * 8];
#pragma unroll
      for (int mi = 0; mi < 4; mi++) {
        acc[mi][ni] = __builtin_amdgcn_mfma_f32_16x16x32_bf16(ah[mi], bh, acc[mi][ni], 0, 0, 0);
        acc[mi][ni] = __builtin_amdgcn_mfma_f32_16x16x32_bf16(ah[mi], bl, acc[mi][ni], 0, 0, 0);
        acc[mi][ni] = __builtin_amdgcn_mfma_f32_16x16x32_bf16(al[mi], bh, acc[mi][ni], 0, 0, 0);
      }
    }
    __syncthreads();
  }
  unsigned long long memb = 0, fb = 0;
#pragma unroll
  for (int mi = 0; mi < 4; mi++)
#pragma unroll
    for (int ni = 0; ni < 4; ni++)
#pragma unroll
      for (int r = 0; r < 4; r++) {
        int e = (mi << 4) | (ni << 2) | r;
        float nqv = nqs[wm + mi * 16 + quad * 4 + r];
        float ncv = ncs[wn + ni * 16 + l16];
        float d2a = nqv + ncv - 2.f * acc[mi][ni][r];
        float eps = 4.0e-5f * (nqv + ncv) + 1.0e-6f;
        if (d2a < r2 - eps) memb |= 1ull << e;
        else if (d2a <= r2 + eps) fb |= 1ull << e;
      }
  while (fb) {
    int e = __builtin_ctzll(fb);
    fb &= fb - 1;
    int mi = e >> 4, ni = (e >> 2) & 3, r = e & 3;
    int qrow = q0 + wm + mi * 16 + quad * 4 + r;
    int ccol = c0 + wn + ni * 16 + l16;
    float a2 = 0.f;
    for (int k = 0; k < C; k++) {
      float d = F32[(size_t)qrow * C + k] - F32[(size_t)ccol * C + k];
      a2 = fmaf(d, d, a2);
    }
    if (a2 <= r2) memb |= 1ull << e;
  }
#pragma unroll
  for (int ni = 0; ni < 4; ni++) {
    int cl = wn + ni * 16 + l16;
    unsigned int w0b = 0, w1b = 0;
#pragma unroll
    for (int mi = 0; mi < 4; mi++)
#pragma unroll
      for (int r = 0; r < 4; r++)
        if (memb & (1ull << ((mi << 4) | (ni << 2) | r))) {
          unsigned int bitpos = ((mi & 1) << 4) | (quad << 2) | r;
          if (mi < 2) w0b |= 1u << bitpos;
          else w1b |= 1u << bitpos;
        }
    if (w0b) atomicOr(&tw[cl][(wm >> 5)], w0b);
    if (w1b) atomicOr(&tw[cl][(wm >> 5) + 1], w1b);
  }
  __syncthreads();
  {
    int row = tid >> 1, half = tid & 1;
    int wq = row >> 5, sb = row & 31;
    unsigned int lo = 0, hi = 0;
    for (int j = 0; j < 32; j++) {
      lo |= ((tw[half * 64 + j][wq] >> sb) & 1u) << j;
      hi |= ((tw[half * 64 + 32 + j][wq] >> sb) & 1u) << j;
    }
    mask[(size_t)(q0 + row) * 32 + (ct << 1) + half] =
        ((unsigned long long)hi << 32) | lo;
  }
  if (qt != ct) {
    int row = tid >> 1, word = tid & 1;
    unsigned long long v = (unsigned long long)tw[row][word * 2] |
                           ((unsigned long long)tw[row][word * 2 + 1] << 32);
    mask[(size_t)(c0 + row) * 32 + (qt << 1) + word] = v;
  }
}

// ---------------------------------------------------------------------------
// MERGE A: sa2_fused (256 blocks) + ball_mask<64> (1088 blocks).
// Both depend only on knn outputs; complementary pipes (VALU vs MFMA).
// ---------------------------------------------------------------------------
__global__ __launch_bounds__(256) void fused_sa2_ball64(
    const float* __restrict__ X1,
    const __hip_bfloat16* __restrict__ X1b,
    const __hip_bfloat16* __restrict__ X1lo,
    const float* __restrict__ nrmX1,
    unsigned long long* __restrict__ MASK, float r2,
    const float* __restrict__ w0, const float* __restrict__ b0,
    const float* __restrict__ w1, const float* __restrict__ b1,
    float* __restrict__ H2)
{
  __shared__ __align__(16) char smem[47616];
  int bid = blockIdx.x;
  if (bid < 1088)
    ball_body<64>(smem, X1, X1b, X1lo, nrmX1, MASK, r2, bid % 136, bid / 136);
  else
    sa2_body(smem, X1, w0, b0, w1, b1, H2, (bid - 1088) << 6);
}

// Standalone ball128 (round-12 behavior).
template <int C>
__global__ __launch_bounds__(256) void ball_mask_mfma(
    const float* __restrict__ F32,
    const __hip_bfloat16* __restrict__ Fhi,
    const __hip_bfloat16* __restrict__ Flo,
    const float* __restrict__ nrm,
    unsigned long long* __restrict__ mask,
    float r2)
{
  __shared__ __align__(16) char smem[44032];
  ball_body<C>(smem, F32, Fhi, Flo, nrm, mask, r2, blockIdx.x, blockIdx.y);
}

// ---------------------------------------------------------------------------
// bf16 MFMA GEMM body (bf16 out). smem >= 20480 B.
// ---------------------------------------------------------------------------
__device__ void mfma_body(char* smem,
    const short* __restrict__ Ag, const short* __restrict__ Bg,
    const float* __restrict__ bias, __hip_bfloat16* __restrict__ Y,
    int lda, int ldw, int ldy, int K, int m0, int n0)
{
  short (*As)[40] = (short(*)[40])smem;
  short (*Bs)[40] = (short(*)[40])(smem + 10240);
  int tid = threadIdx.x;
  int wave = tid >> 6, lane = tid & 63;
  int quad = lane >> 4, l16 = lane & 15;
  int wm = (wave >> 1) << 6, wn = (wave & 1) << 6;
  f32x4 acc[4][4] = {};
  int srow = tid >> 2, sq = tid & 3;
  for (int k0 = 0; k0 < K; k0 += 32) {
#pragma unroll
    for (int h = 0; h < 2; h++) {
      int r = srow + (h << 6);
      uint4 va = *(const uint4*)&Ag[(size_t)(m0 + r) * lda + k0 + sq * 8];
      *(uint4*)&As[r][sq * 8] = va;
      uint4 vb = *(const uint4*)&Bg[(size_t)(n0 + r) * ldw + k0 + sq * 8];
      *(uint4*)&Bs[r][sq * 8] = vb;
    }
    __syncthreads();
    short8 a[4], b[4];
#pragma unroll
    for (int mi = 0; mi < 4; mi++)
      a[mi] = *(const short8*)&As[wm + mi * 16 + l16][quad * 8];
#pragma unroll
    for (int ni = 0; ni < 4; ni++)
      b[ni] = *(const short8*)&Bs[wn + ni * 16 + l16][quad * 8];
#pragma unroll
    for (int mi = 0; mi < 4; mi++)
#pragma unroll
      for (int ni = 0; ni < 4; ni++)
        acc[mi][ni] = __builtin_amdgcn_mfma_f32_16x16x32_bf16(
            a[mi], b[ni], acc[mi][ni], 0, 0, 0);
    __syncthreads();
  }
  float bn[4];
#pragma unroll
  for (int ni = 0; ni < 4; ni++) bn[ni] = bias[n0 + wn + ni * 16 + l16];
#pragma unroll
  for (int mi = 0; mi < 4; mi++)
#pragma unroll
    for (int ni = 0; ni < 4; ni++) {
      int n = n0 + wn + ni * 16 + l16;
#pragma unroll
      for (int r = 0; r < 4; r++) {
        int m = m0 + wm + mi * 16 + quad * 4 + r;
        float v = fmaxf(acc[mi][ni][r] + bn[ni], 0.f);
        Y[(size_t)m * ldy + n] = (__hip_bfloat16)v;
      }
    }
}

__global__ __launch_bounds__(256) void gemm_mfma_bf16(
    const __hip_bfloat16* __restrict__ A, int lda,
    const __hip_bfloat16* __restrict__ Wt, int ldw,
    const float* __restrict__ bias,
    __hip_bfloat16* __restrict__ Y, int ldy, int K)
{
  __shared__ __align__(16) char smem[20480];
  mfma_body(smem, (const short*)A, (const short*)Wt, bias, Y,
            lda, ldw, ldy, K, blockIdx.y << 7, blockIdx.x << 7);
}

struct GJobs {
  const short* A[3];
  const short* W[3];
  const float* bias[3];
  __hip_bfloat16* Y[3];
  int lda[3], ldw[3], ldy[3], N[3], K[3], xt[3], off[3];
};

__global__ __launch_bounds__(256) void gemm_mfma_multi(GJobs g)
{
  __shared__ __align__(16) char smem[20480];
  int bid = blockIdx.x;
  int j = 0;
#pragma unroll
  for (int t = 1; t < 3; t++)
    if (bid >= g.off[t]) j = t;
  int rel = bid - g.off[j];
  mfma_body(smem, g.A[j], g.W[j], g.bias[j], g.Y[j],
            g.lda[j], g.ldw[j], g.ldy[j], g.K[j],
            (rel / g.xt[j]) << 7, (rel % g.xt[j]) << 7);
}

// ---------------------------------------------------------------------------
// gather bf16 body (4 queries/block, one per wave; no __syncthreads).
// LDS: idxl 0..1024, wtab 1024..2048, scount 2048..2064.
// ---------------------------------------------------------------------------
__device__ void gather_bf16_body(char* smem, int blk,
    const unsigned long long* __restrict__ mask,
    const __hip_bfloat16* __restrict__ H, int CH,
    __hip_bfloat16* __restrict__ Yb, int ldy, int S)
{
  int (*idxl)[64] = (int(*)[64])smem;
  float (*wtab)[64] = (float(*)[64])(smem + 1024);
  int* scount = (int*)(smem + 2048);
  int tid = threadIdx.x;
  int wave = tid >> 6, lane = tid & 63;
  int q = ((blk & 7) << 11) + ((blk >> 3) << 2) + wave;
  int base = q & ~2047;
  if (lane < 32) {
    unsigned long long w = mask[(size_t)q * 32 + lane];
    int cnt = __popcll(w);
    int inc = cnt;
#pragma unroll
    for (int off = 1; off < 32; off <<= 1) {
      int o = __shfl_up(inc, off);
      if (lane >= off) inc += o;
    }
    if (lane == 31) scount[wave] = inc;
    int p = inc - cnt;
    while (w && p < 64) {
      int j = (lane << 6) + __builtin_ctzll(w);
      w &= w - 1;
      idxl[wave][p++] = j;
    }
  }
  int c = scount[wave];
  {
    int p = lane;
    int cnt = (p < c && p < S) ? ((S - 1 - p) / c + 1) : 0;
    wtab[wave][p] = (float)cnt / (float)S;
  }
  const unsigned short* Hs = (const unsigned short*)H;
  float acc[4] = {0.f, 0.f, 0.f, 0.f};
  int lim = c < S ? c : S;
#pragma unroll 4
  for (int s = 0; s < lim; s++) {
    float wv = wtab[wave][s];
    uint2 v = *(const uint2*)&Hs[(size_t)(base + idxl[wave][s]) * CH + lane * 4];
    acc[0] += wv * __uint_as_float(v.x << 16);
    acc[1] += wv * __uint_as_float(v.x & 0xffff0000u);
    acc[2] += wv * __uint_as_float(v.y << 16);
    acc[3] += wv * __uint_as_float(v.y & 0xffff0000u);
  }
  int n0 = lane * 4;
#pragma unroll
  for (int j = 0; j < 4; j++)
    Yb[(size_t)q * ldy + n0 + j] = (__hip_bfloat16)acc[j];
}

// ---------------------------------------------------------------------------
// MERGE B tail: fp1-l2 + fp2-l2 MFMA jobs (768 blocks) + gather3 (4096).
// Disjoint G columns; inputs independent.
// ---------------------------------------------------------------------------
struct GJobs2 {
  const short* A[2];
  const short* W[2];
  const float* bias[2];
  __hip_bfloat16* Y[2];
  int lda[2], ldw[2], ldy[2], K[2], xt[2], off[2];
};

__global__ __launch_bounds__(256) void fused_tail(
    GJobs2 g, int goff,
    const unsigned long long* __restrict__ mask,
    const __hip_bfloat16* __restrict__ H, int CH,
    __hip_bfloat16* __restrict__ Yb, int ldy, int S)
{
  __shared__ __align__(16) char smem[20480];
  int bid = blockIdx.x;
  if (bid < goff) {
    int j = (bid >= g.off[1]) ? 1 : 0;
    int rel = bid - g.off[j];
    mfma_body(smem, g.A[j], g.W[j], g.bias[j], g.Y[j],
              g.lda[j], g.ldw[j], g.ldy[j], g.K[j],
              (rel / g.xt[j]) << 7, (rel % g.xt[j]) << 7);
    return;
  }
  gather_bf16_body(smem, bid - goff, mask, H, CH, Yb, ldy, S);
}

// ---------------------------------------------------------------------------
// gather2 fp32 (round-17 version, passing).
// ---------------------------------------------------------------------------
__global__ __launch_bounds__(256) void ball_gather4_f32(
    const unsigned long long* __restrict__ mask,
    const float* __restrict__ H, int CH,
    float* __restrict__ Yf, __hip_bfloat16* __restrict__ Yb,
    __hip_bfloat16* __restrict__ Ylo, float* __restrict__ nrm,
    int ldy, int S)
{
  int blk = blockIdx.x;
  int tid = threadIdx.x;
  int wave = tid >> 6, lane = tid & 63;
  int q = ((blk & 7) << 11) + ((blk >> 3) << 2) + wave;
  int base = q & ~2047;
  __shared__ int idxl[4][64];
  __shared__ float wtab[4][64];
  __shared__ int scount[4];
  if (lane < 32) {
    unsigned long long w = mask[(size_t)q * 32 + lane];
    int cnt = __popcll(w);
    int inc = cnt;
#pragma unroll
    for (int off = 1; off < 32; off <<= 1) {
      int o = __shfl_up(inc, off);
      if (lane >= off) inc += o;
    }
    if (lane == 31) scount[wave] = inc;
    int p = inc - cnt;
    while (w && p < 64) {
      int j = (lane << 6) + __builtin_ctzll(w);
      w &= w - 1;
      idxl[wave][p++] = j;
    }
  }
  int c = scount[wave];
  {
    int p = lane;
    int cnt = (p < c && p < S) ? ((S - 1 - p) / c + 1) : 0;
    wtab[wave][p] = (float)cnt / (float)S;
  }
  float acc0 = 0.f, acc1 = 0.f;
  int lim = c < S ? c : S;
#pragma unroll 4
  for (int s = 0; s < lim; s++) {
    float wv = wtab[wave][s];
    float2 v = *(const float2*)&H[(size_t)(base + idxl[wave][s]) * CH + lane * 2];
    acc0 += wv * v.x;
    acc1 += wv * v.y;
  }
  int n0 = lane * 2;
  if (Yf) *(float2*)&Yf[(size_t)q * ldy + n0] = make_float2(acc0, acc1);
  if (Yb) {
    Yb[(size_t)q * ldy + n0] = (__hip_bfloat16)acc0;
    Yb[(size_t)q * ldy + n0 + 1] = (__hip_bfloat16)acc1;
  }
  if (Ylo) {
    __hip_bfloat16 h0 = (__hip_bfloat16)acc0, h1 = (__hip_bfloat16)acc1;
    Ylo[(size_t)q * ldy + n0] = (__hip_bfloat16)(acc0 - (float)h0);
    Ylo[(size_t)q * ldy + n0 + 1] = (__hip_bfloat16)(acc1 - (float)h1);
  }
  if (nrm) {
    float nv = acc0 * acc0 + acc1 * acc1;
#pragma unroll
    for (int off = 32; off > 0; off >>= 1) nv += __shfl_down(nv, off);
    if (lane == 0) nrm[q] = nv;
  }
}

// ---------------------------------------------------------------------------
// fc2 + out head fused (unchanged).
// ---------------------------------------------------------------------------
__global__ __launch_bounds__(256) void gemm_fc2_out(
    const __hip_bfloat16* __restrict__ A,
    const __hip_bfloat16* __restrict__ Wt,
    const float* __restrict__ bias,
    const float* __restrict__ wout,
    const float* __restrict__ bout,
    float* __restrict__ out)
{
  __shared__ __align__(16) short As[128][40];
  __shared__ __align__(16) short Bs[128][40];
  __shared__ float red[128][2];
  const int N = 128, K = 256, lda = 256, ldw = 256;
  int tid = threadIdx.x;
  int wave = tid >> 6, lane = tid & 63;
  int quad = lane >> 4, l16 = lane & 15;
  int m0 = blockIdx.y << 7;
  int wm = (wave >> 1) << 6, wn = (wave & 1) << 6;
  f32x4 acc[4][4] = {};
  const short* Ag = (const short*)A;
  const short* Bg = (const short*)Wt;
  int srow = tid >> 2, sq = tid & 3;
  for (int k0 = 0; k0 < K; k0 += 32) {
#pragma unroll
    for (int h = 0; h < 2; h++) {
      int r = srow + (h << 6);
      uint4 va = *(const uint4*)&Ag[(size_t)(m0 + r) * lda + k0 + sq * 8];
      *(uint4*)&As[r][sq * 8] = va;
      uint4 vb = *(const uint4*)&Bg[(size_t)(r % N) * ldw + k0 + sq * 8];
      *(uint4*)&Bs[r][sq * 8] = vb;
    }
    __syncthreads();
    short8 a[4], b[4];
#pragma unroll
    for (int mi = 0; mi < 4; mi++)
      a[mi] = *(const short8*)&As[wm + mi * 16 + l16][quad * 8];
#pragma unroll
    for (int ni = 0; ni < 4; ni++)
      b[ni] = *(const short8*)&Bs[wn + ni * 16 + l16][quad * 8];
#pragma unroll
    for (int mi = 0; mi < 4; mi++)
#pragma unroll
      for (int ni = 0; ni < 4; ni++)
        acc[mi][ni] = __builtin_amdgcn_mfma_f32_16x16x32_bf16(
            a[mi], b[ni], acc[mi][ni], 0, 0, 0);
    __syncthreads();
  }
  float bn[4], wo[4];
#pragma unroll
  for (int ni = 0; ni < 4; ni++) {
    int n = wn + ni * 16 + l16;
    bn[ni] = bias[n];
    wo[ni] = wout[n];
  }
  float sacc[4][4];
#pragma unroll
  for (int mi = 0; mi < 4; mi++)
#pragma unroll
    for (int r = 0; r < 4; r++) {
      float s = 0.f;
#pragma unroll
      for (int ni = 0; ni < 4; ni++)
        s += fmaxf(acc[mi][ni][r] + bn[ni], 0.f) * wo[ni];
      sacc[mi][r] = s;
    }
#pragma unroll
  for (int off = 1; off < 16; off <<= 1)
#pragma unroll
    for (int mi = 0; mi < 4; mi++)
#pragma unroll
      for (int r = 0; r < 4; r++)
        sacc[mi][r] += __shfl_xor(sacc[mi][r], off);
  int wp = wave & 1;
  if (l16 == 0) {
#pragma unroll
    for (int mi = 0; mi < 4; mi++)
#pragma unroll
      for (int r = 0; r < 4; r++)
        red[wm + mi * 16 + quad * 4 + r][wp] = sacc[mi][r];
  }
  __syncthreads();
  if (tid < 128) {
    float s = red[tid][0] + red[tid][1] + bout[0];
    out[(size_t)(m0 + tid)] = 1.f / (1.f + expf(-s));
  }
}

// ---------------------------------------------------------------------------
// SA1 KNN v9 (round-15..17 version, passing — bit-identical selection).
// ---------------------------------------------------------------------------
__global__ __launch_bounds__(256) void knn_mean4(
    const float* __restrict__ X,
    const float* __restrict__ G1,
    float* __restrict__ X1,
    __hip_bfloat16* __restrict__ X1b,
    __hip_bfloat16* __restrict__ X1lo,
    float* __restrict__ nrmX1)
{
  int blk = blockIdx.x;
  int qb = ((blk & 7) << 11) + ((blk >> 3) << 2);
  int base = qb & ~2047;
  int tid = threadIdx.x;
  int wave = tid >> 6, lane = tid & 63;
  __shared__ unsigned long long lmins[4][256];
  __shared__ unsigned long long qmins[4][64];
  __shared__ unsigned long long thr[4];
  __shared__ unsigned long long surv[4][256];
  __shared__ int scnt[4];
  __shared__ int selidx[4][32];
  if (tid < 4) scnt[tid] = 0;
  float xj[8], yj[8];
#pragma unroll
  for (int u = 0; u < 8; u++) {
    int j = (u << 8) + tid;
    float2 c = *(const float2*)&X[(size_t)(base + j) * 2];
    xj[u] = c.x;
    yj[u] = c.y;
  }
  unsigned long long key[4][8];
#pragma unroll
  for (int g = 0; g < 4; g++) {
    float qx = X[(size_t)(qb + g) * 2];
    float qy = X[(size_t)(qb + g) * 2 + 1];
    unsigned long long lm = ~0ull;
#pragma unroll
    for (int u = 0; u < 8; u++) {
      float dx = xj[u] - qx;
      float dy = yj[u] - qy;
      float d2 = dx * dx + dy * dy;
      key[g][u] = ((unsigned long long)__float_as_uint(d2) << 32) |
                  (unsigned)((u << 8) + tid);
      lm = umin64(lm, key[g][u]);
    }
    lmins[g][tid] = lm;
  }
  __syncthreads();
  {
    int g = wave;
    unsigned long long qm =
        umin64(umin64(lmins[g][lane], lmins[g][lane + 64]),
               umin64(lmins[g][lane + 128], lmins[g][lane + 192]));
    qmins[g][lane] = qm;
    int rank = 0;
    for (int i = 0; i < 64; i++) rank += (qmins[g][i] < qm);
    if (rank == 31) thr[g] = qm;
  }
  __syncthreads();
#pragma unroll
  for (int g = 0; g < 4; g++) {
    unsigned long long T = thr[g];
#pragma unroll
    for (int u = 0; u < 8; u++) {
      if (key[g][u] <= T) {
        int p = atomicAdd(&scnt[g], 1);
        if (p < 256) surv[g][p] = key[g][u];
      }
    }
  }
  __syncthreads();
  int ovf[4] = {scnt[0], scnt[1], scnt[2], scnt[3]};
  {
    int g = wave;
    int s = ovf[g];
    if (s <= 256) {
      for (int i = lane; i < s; i += 64) {
        unsigned long long c = surv[g][i];
        int r = 0;
        for (int j2 = 0; j2 < s; j2++) r += (surv[g][j2] < c);
        if (r < 32) selidx[g][r] = (int)(c & 0xffffffffULL);
      }
    }
  }
  if (ovf[0] > 256 || ovf[1] > 256 || ovf[2] > 256 || ovf[3] > 256) {
    unsigned long long* ob = &lmins[0][0];
    for (int g = 0; g < 4; g++) {
      if (ovf[g] <= 256) continue;
      __syncthreads();
      if (tid == 0) scnt[g] = 0;
      __syncthreads();
      unsigned long long T = thr[g];
#pragma unroll
      for (int u = 0; u < 8; u++) {
        if (key[g][u] <= T) {
          int p = atomicAdd(&scnt[g], 1);
          ob[p] = key[g][u];
        }
      }
      __syncthreads();
      int s2 = scnt[g];
      for (int i = tid; i < s2; i += 256) {
        unsigned long long c = ob[i];
        int r = 0;
        for (int j2 = 0; j2 < s2; j2++) r += (ob[j2] < c);
        if (r < 32) selidx[g][r] = (int)(c & 0xffffffffULL);
      }
    }
    __syncthreads();
  }
  {
    int g = wave;
    float acc = 0.f;
#pragma unroll 8
    for (int sI = 0; sI < 32; sI++)
      acc += G1[(size_t)(base + selidx[g][sI]) * 64 + lane];
    float v = acc * (1.0f / 32.0f);
    int q = qb + g;
    X1[(size_t)q * 64 + lane] = v;
    __hip_bfloat16 hi = (__hip_bfloat16)v;
    X1b[(size_t)q * 64 + lane] = hi;
    X1lo[(size_t)q * 64 + lane] = (__hip_bfloat16)(v - (float)hi);
    float nv = v * v;
#pragma unroll
    for (int off = 32; off > 0; off >>= 1) nv += __shfl_down(nv, off);
    if (lane == 0) nrmX1[q] = nv;
  }
}

// ---------------------------------------------------------------------------
extern "C" void kernel_launch(void* const* d_in, const int* in_sizes, int n_in,
                              void* d_out, int out_size, void* d_ws,
                              size_t ws_size, hipStream_t stream)
{
  const float* x      = (const float*)d_in[0];
  const float* sa1_w0 = (const float*)d_in[1];
  const float* sa1_b0 = (const float*)d_in[2];
  const float* sa1_w1 = (const float*)d_in[3];
  const float* sa1_b1 = (const float*)d_in[4];
  const float* sa2_w0 = (const float*)d_in[5];
  const float* sa2_b0 = (const float*)d_in[6];
  const float* sa2_w1 = (const float*)d_in[7];
  const float* sa2_b1 = (const float*)d_in[8];
  const float* sa3_w0 = (const float*)d_in[9];
  const float* sa3_b0 = (const float*)d_in[10];
  const float* sa3_w1 = (const float*)d_in[11];
  const float* sa3_b1 = (const float*)d_in[12];
  const float* fp1_w0 = (const float*)d_in[13];
  const float* fp1_b0 = (const float*)d_in[14];
  const float* fp1_w1 = (const float*)d_in[15];
  const float* fp1_b1 = (const float*)d_in[16];
  const float* fp2_w0 = (const float*)d_in[17];
  const float* fp2_b0 = (const float*)d_in[18];
  const float* fp2_w1 = (const float*)d_in[19];
  const float* fp2_b1 = (const float*)d_in[20];
  const float* fc1_w  = (const float*)d_in[21];
  const float* fc1_b  = (const float*)d_in[22];
  const float* fc2_w  = (const float*)d_in[23];
  const float* fc2_b  = (const float*)d_in[24];
  const float* out_w  = (const float*)d_in[25];
  const float* out_b  = (const float*)d_in[26];
  float* out = (float*)d_out;

  const size_t M = M_ROWS;
  float* ws = (float*)d_ws;
  float* G1  = ws + M * 256;
  float* X1  = ws + M * 320;
  float* X2  = ws + M * 384;
  float* H2  = ws + M * 512;
  __hip_bfloat16* H3b16 = (__hip_bfloat16*)(ws + M * 640);
  unsigned long long* MASK = (unsigned long long*)(ws + M * 896);
  __hip_bfloat16* X1b = (__hip_bfloat16*)(ws + M * 960);
  __hip_bfloat16* X2b = (__hip_bfloat16*)(ws + M * 992);
  __hip_bfloat16* TB0 = (__hip_bfloat16*)(ws + M * 1056);
  __hip_bfloat16* TB1 = (__hip_bfloat16*)(ws + M * 1184);
  __hip_bfloat16* TB2 = (__hip_bfloat16*)(ws + M * 1440);
  __hip_bfloat16* G   = (__hip_bfloat16*)(ws + M * 1568);
  __hip_bfloat16* H3b = (__hip_bfloat16*)(ws + M * 2080);
  __hip_bfloat16* WB  = (__hip_bfloat16*)(ws + M * 2208);
  __hip_bfloat16* X1lo = (__hip_bfloat16*)(ws + M * 2240);
  __hip_bfloat16* X2lo = (__hip_bfloat16*)(ws + M * 2272);
  float* nrmX1 = ws + M * 2336;
  float* nrmX2 = ws + M * 2337;
  if (ws_size < (size_t)M * 2340 * sizeof(float)) return;
  __hip_bfloat16* w_sa3_0 = WB;
  __hip_bfloat16* w_sa3_1 = w_sa3_0 + 32768;
  __hip_bfloat16* w_fp1_0 = w_sa3_1 + 65536;
  __hip_bfloat16* w_fp1_1 = w_fp1_0 + 65536;
  __hip_bfloat16* w_fp2_0 = w_fp1_1 + 262144;
  __hip_bfloat16* w_fp2_1 = w_fp2_0 + 16384;
  __hip_bfloat16* w_fc1   = w_fp2_1 + 65536;
  __hip_bfloat16* w_fc2   = w_fc1 + 262144;

  dim3 blk(256);
  TJobs jb;
  const float* srcs[8] = {sa3_w0, sa3_w1, fp1_w0, fp1_w1, fp2_w0, fp2_w1, fc1_w, fc2_w};
  __hip_bfloat16* dsts[8] = {w_sa3_0, w_sa3_1, w_fp1_0, w_fp1_1, w_fp2_0, w_fp2_1, w_fc1, w_fc2};
  int Ks[8] = {128, 256, 128, 512, 64, 256, 1024, 256};
  int Ns[8] = {256, 256, 512, 512, 256, 256, 256, 128};
  int off = 0;
  for (int i = 0; i < 8; i++) {
    jb.W[i] = srcs[i]; jb.Wt[i] = dsts[i];
    jb.K[i] = Ks[i]; jb.N[i] = Ns[i];
    jb.bx[i] = Ns[i] >> 5;
    jb.off[i] = off;
    off += (Ns[i] >> 5) * (Ks[i] >> 5);
  }
  prologue_kernel<<<off + 256, blk, 0, stream>>>(jb, off, x, sa1_w0, sa1_b0,
                                                 sa1_w1, sa1_b1, G1);
  knn_mean4<<<4096, 256, 0, stream>>>(x, G1, X1, X1b, X1lo, nrmX1);
  // MERGE A: sa2 MLP + ball64 (both depend only on knn outputs).
  fused_sa2_ball64<<<1088 + 256, blk, 0, stream>>>(
      X1, X1b, X1lo, nrmX1, MASK, 0.2f * 0.2f,
      sa2_w0, sa2_b0, sa2_w1, sa2_b1, H2);
  ball_gather4_f32<<<4096, blk, 0, stream>>>(MASK, H2, 128, X2, X2b, X2lo, nrmX2, 128, 32);
  // ball128, then g1 triple, then sa3-l2 (gather3's true dependency).
  ball_mask_mfma<128><<<dim3(136, 8), blk, 0, stream>>>(X2, X2b, X2lo, nrmX2, MASK, 0.4f * 0.4f);
  {
    GJobs g1;
    g1.A[0] = (const short*)X2b; g1.W[0] = (const short*)w_sa3_0; g1.bias[0] = sa3_b0;
    g1.Y[0] = TB0; g1.lda[0] = 128; g1.ldw[0] = 128; g1.ldy[0] = 256; g1.N[0] = 256; g1.K[0] = 128;
    g1.A[1] = (const short*)X2b; g1.W[1] = (const short*)w_fp1_0; g1.bias[1] = fp1_b0;
    g1.Y[1] = TB1; g1.lda[1] = 128; g1.ldw[1] = 128; g1.ldy[1] = 512; g1.N[1] = 512; g1.K[1] = 128;
    g1.A[2] = (const short*)X1b; g1.W[2] = (const short*)w_fp2_0; g1.bias[2] = fp2_b0;
    g1.Y[2] = TB2; g1.lda[2] = 64; g1.ldw[2] = 64; g1.ldy[2] = 256; g1.N[2] = 256; g1.K[2] = 64;
    int tot1 = 0;
    for (int i = 0; i < 3; i++) {
      g1.xt[i] = g1.N[i] >> 7;
      g1.off[i] = tot1;
      tot1 += g1.xt[i] * 128;
    }
    gemm_mfma_multi<<<tot1, blk, 0, stream>>>(g1);
  }
  // sa3-l2 alone (256 blocks): H3b16 = relu(TB0 @ w_sa3_1 + b).
  gemm_mfma_bf16<<<dim3(2, 128), blk, 0, stream>>>(TB0, 256, w_sa3_1, 256,
                                                   sa3_b1, H3b16, 256, 256);
  // MERGE B: fp1-l2 + fp2-l2 + gather3 in one dispatch.
  {
    GJobs2 g2;
    g2.A[0] = (const short*)TB1; g2.W[0] = (const short*)w_fp1_1; g2.bias[0] = fp1_b1;
    g2.Y[0] = G + 256; g2.lda[0] = 512; g2.ldw[0] = 512; g2.ldy[0] = 1024; g2.K[0] = 512;
    g2.xt[0] = 4; g2.off[0] = 0;                 // 512 blocks
    g2.A[1] = (const short*)TB2; g2.W[1] = (const short*)w_fp2_1; g2.bias[1] = fp2_b1;
    g2.Y[1] = G; g2.lda[1] = 256; g2.ldw[1] = 256; g2.ldy[1] = 1024; g2.K[1] = 256;
    g2.xt[1] = 2; g2.off[1] = 512;               // 256 blocks
    int goff = 768;
    fused_tail<<<goff + 4096, blk, 0, stream>>>(g2, goff, MASK, H3b16, 256,
                                                G + 768, 1024, 64);
  }
  // Head: fc1 (bf16), then fc2+out fused.
  gemm_mfma_bf16<<<dim3(2, 128), blk, 0, stream>>>(G, 1024, w_fc1, 1024,
                                                   fc1_b, H3b, 256, 1024);
  gemm_fc2_out<<<dim3(1, 128), blk, 0, stream>>>(H3b, w_fc2, fc2_b, out_w, out_b, out);
}

// Round 19
// 350.164 us; speedup vs baseline: 1.0394x; 1.0394x over previous
//
#include <hip/hip_runtime.h>
#include <hip/hip_bf16.h>
#include <cstdint>

#define M_ROWS 16384

typedef __attribute__((ext_vector_type(8))) short short8;
typedef __attribute__((ext_vector_type(4))) float f32x4;

__device__ __forceinline__ unsigned long long umin64(unsigned long long a,
                                                     unsigned long long b) {
  return a < b ? a : b;
}

// ---------------------------------------------------------------------------
// PROLOGUE: 8 weight transposes + SA1 fused MLP in one dispatch.
// ---------------------------------------------------------------------------
struct TJobs {
  const float* W[8];
  __hip_bfloat16* Wt[8];
  int K[8], N[8], bx[8], off[8];
};

__global__ __launch_bounds__(256) void prologue_kernel(
    TJobs jb, int toff,
    const float* __restrict__ x,
    const float* __restrict__ w0,
    const float* __restrict__ b0,
    const float* __restrict__ w1,
    const float* __restrict__ b1,
    float* __restrict__ G1)
{
  __shared__ float tile[32][33];
  __shared__ __align__(16) float Ts[64][68];
  __shared__ __align__(16) float Ws[64][68];
  __shared__ float xs[64][2];
  __shared__ float w0s[2][64];
  __shared__ float b0s[64];
  int bid = blockIdx.x;
  int tid = threadIdx.x;
  if (bid < toff) {
    int j = 0;
#pragma unroll
    for (int t = 1; t < 8; t++)
      if (bid >= jb.off[t]) j = t;
    int rel = bid - jb.off[j];
    int K = jb.K[j], N = jb.N[j];
    const float* W = jb.W[j];
    __hip_bfloat16* Wt = jb.Wt[j];
    int n0 = (rel % jb.bx[j]) << 5, k0 = (rel / jb.bx[j]) << 5;
    int c = tid & 31, i0 = tid >> 5;
#pragma unroll
    for (int p = 0; p < 4; p++) {
      int i = i0 + p * 8;
      tile[i][c] = W[(size_t)(k0 + i) * N + n0 + c];
    }
    __syncthreads();
#pragma unroll
    for (int p = 0; p < 4; p++) {
      int r = i0 + p * 8;
      Wt[(size_t)(n0 + r) * K + k0 + c] = (__hip_bfloat16)tile[c][r];
    }
    return;
  }
  int m0 = (bid - toff) << 6;
  if (tid < 128) {
    ((float*)xs)[tid] = x[(size_t)m0 * 2 + tid];
  } else if (tid < 192) {
    int n = tid - 128;
    w0s[0][n] = w0[n];
    b0s[n] = b0[n];
  } else {
    int n = tid - 192;
    w0s[1][n] = w0[64 + n];
  }
#pragma unroll
  for (int i = 0; i < 16; i++) {
    int idx = tid + (i << 8);
    int k = idx >> 6, n = idx & 63;
    Ws[k][n] = w1[(size_t)k * 64 + n];
  }
  __syncthreads();
#pragma unroll
  for (int i = 0; i < 16; i++) {
    int idx = tid + (i << 8);
    int m = idx >> 6, n = idx & 63;
    float acc = 0.f;
    acc += xs[m][0] * w0s[0][n];
    acc += xs[m][1] * w0s[1][n];
    Ts[n][m] = fmaxf(acc + b0s[n], 0.f);
  }
  __syncthreads();
  int tx = tid & 15, ty = tid >> 4;
  float acc[4][4] = {};
  for (int k = 0; k < 64; k++) {
    float4 a4 = *(const float4*)&Ts[k][ty << 2];
    float4 b4 = *(const float4*)&Ws[k][tx << 2];
    float av[4] = {a4.x, a4.y, a4.z, a4.w};
    float bv[4] = {b4.x, b4.y, b4.z, b4.w};
#pragma unroll
    for (int i = 0; i < 4; i++)
#pragma unroll
      for (int j = 0; j < 4; j++)
        acc[i][j] += av[i] * bv[j];
  }
  float4 bb = *(const float4*)&b1[tx << 2];
  float bv[4] = {bb.x, bb.y, bb.z, bb.w};
#pragma unroll
  for (int i = 0; i < 4; i++) {
    int m = m0 + (ty << 2) + i;
    float4 o;
    o.x = fmaxf(acc[i][0] + bv[0], 0.f);
    o.y = fmaxf(acc[i][1] + bv[1], 0.f);
    o.z = fmaxf(acc[i][2] + bv[2], 0.f);
    o.w = fmaxf(acc[i][3] + bv[3], 0.f);
    *(float4*)&G1[(size_t)m * 64 + (tx << 2)] = o;
  }
}

// ---------------------------------------------------------------------------
// SA2 fused standalone (round-16/17 operating point — bit-identical H2).
// [Round-18 lesson: merging this with ball64 coupled VGPR/LDS budgets and
//  dropped occupancy to 9.5% — 66 µs vs 45 serial. Keep standalone.]
// ---------------------------------------------------------------------------
__global__ __launch_bounds__(256) void sa2_fused(
    const float* __restrict__ X1,
    const float* __restrict__ w0,
    const float* __restrict__ b0,
    const float* __restrict__ w1,
    const float* __restrict__ b1,
    float* __restrict__ H2)
{
  __shared__ __align__(16) float Ts[128][68];
  __shared__ __align__(16) float Bs[16][132];
  __shared__ __align__(16) float Xs[16][68];
  int tid = threadIdx.x;
  int tx = tid & 15, ty = tid >> 4;
  int m0 = blockIdx.x << 6;
  float acc1[4][8] = {};
  for (int k0 = 0; k0 < 64; k0 += 16) {
#pragma unroll
    for (int i = 0; i < 4; i++) {
      int idx = tid + (i << 8);
      int m = idx >> 4, k = idx & 15;
      Xs[k][m] = X1[(size_t)(m0 + m) * 64 + k0 + k];
    }
#pragma unroll
    for (int i = 0; i < 8; i++) {
      int idx = tid + (i << 8);
      int n = idx & 127, k = idx >> 7;
      Bs[k][n] = w0[(size_t)(k0 + k) * 128 + n];
    }
    __syncthreads();
#pragma unroll
    for (int k = 0; k < 16; k++) {
      float av[4], bv[8];
#pragma unroll
      for (int i = 0; i < 4; i++) av[i] = Xs[k][ty * 4 + i];
#pragma unroll
      for (int j = 0; j < 8; j++) bv[j] = Bs[k][tx * 8 + j];
#pragma unroll
      for (int i = 0; i < 4; i++)
#pragma unroll
        for (int j = 0; j < 8; j++)
          acc1[i][j] += av[i] * bv[j];
    }
    __syncthreads();
  }
#pragma unroll
  for (int j = 0; j < 8; j++) {
    float bbv = b0[tx * 8 + j];
#pragma unroll
    for (int i = 0; i < 4; i++)
      Ts[tx * 8 + j][ty * 4 + i] = fmaxf(acc1[i][j] + bbv, 0.f);
  }
  __syncthreads();
  float acc2[4][8] = {};
  for (int k0 = 0; k0 < 128; k0 += 16) {
#pragma unroll
    for (int i = 0; i < 8; i++) {
      int idx = tid + (i << 8);
      int n = idx & 127, k = idx >> 7;
      Bs[k][n] = w1[(size_t)(k0 + k) * 128 + n];
    }
    __syncthreads();
#pragma unroll
    for (int k = 0; k < 16; k++) {
      float av[4], bv[8];
#pragma unroll
      for (int i = 0; i < 4; i++) av[i] = Ts[k0 + k][ty * 4 + i];
#pragma unroll
      for (int j = 0; j < 8; j++) bv[j] = Bs[k][tx * 8 + j];
#pragma unroll
      for (int i = 0; i < 4; i++)
#pragma unroll
        for (int j = 0; j < 8; j++)
          acc2[i][j] += av[i] * bv[j];
    }
    __syncthreads();
  }
#pragma unroll
  for (int i = 0; i < 4; i++) {
    int m = m0 + ty * 4 + i;
#pragma unroll
    for (int j = 0; j < 8; j++) {
      int n = tx * 8 + j;
      H2[(size_t)m * 128 + n] = fmaxf(acc2[i][j] + b1[n], 0.f);
    }
  }
}

// ---------------------------------------------------------------------------
// Ball-mask (split-bf16 MFMA gram + exact guard band; bit-identical masks).
// ---------------------------------------------------------------------------
template <int C>
__global__ __launch_bounds__(256) void ball_mask_mfma(
    const float* __restrict__ F32,
    const __hip_bfloat16* __restrict__ Fhi,
    const __hip_bfloat16* __restrict__ Flo,
    const float* __restrict__ nrm,
    unsigned long long* __restrict__ mask,
    float r2)
{
  __shared__ __align__(16) short Qh[128][40];
  __shared__ __align__(16) short Ql[128][40];
  __shared__ __align__(16) short Ch[128][40];
  __shared__ __align__(16) short Cl[128][40];
  __shared__ unsigned int tw[128][4];
  __shared__ float nqs[128], ncs[128];
  int tid = threadIdx.x;
  int p = blockIdx.x;
  int qt = 0;
  while (p >= 16 - qt) { p -= 16 - qt; qt++; }
  int ct = qt + p;
  int b0 = blockIdx.y << 11;
  int q0 = b0 + (qt << 7), c0 = b0 + (ct << 7);
  tw[tid >> 1][(tid & 1) * 2] = 0;
  tw[tid >> 1][(tid & 1) * 2 + 1] = 0;
  if (tid < 128) nqs[tid] = nrm[q0 + tid];
  else ncs[tid - 128] = nrm[c0 + tid - 128];

  int wave = tid >> 6, lane = tid & 63;
  int quad = lane >> 4, l16 = lane & 15;
  int wm = (wave >> 1) << 6, wn = (wave & 1) << 6;
  f32x4 acc[4][4] = {};
  const short* QH = (const short*)Fhi;
  const short* QL = (const short*)Flo;
  int srow = tid >> 2, sq = tid & 3;
  for (int k0 = 0; k0 < C; k0 += 32) {
#pragma unroll
    for (int h = 0; h < 2; h++) {
      int r = srow + (h << 6);
      *(uint4*)&Qh[r][sq * 8] = *(const uint4*)&QH[(size_t)(q0 + r) * C + k0 + sq * 8];
      *(uint4*)&Ql[r][sq * 8] = *(const uint4*)&QL[(size_t)(q0 + r) * C + k0 + sq * 8];
      *(uint4*)&Ch[r][sq * 8] = *(const uint4*)&QH[(size_t)(c0 + r) * C + k0 + sq * 8];
      *(uint4*)&Cl[r][sq * 8] = *(const uint4*)&QL[(size_t)(c0 + r) * C + k0 + sq * 8];
    }
    __syncthreads();
    short8 ah[4], al[4];
#pragma unroll
    for (int mi = 0; mi < 4; mi++) {
      ah[mi] = *(const short8*)&Qh[wm + mi * 16 + l16][quad * 8];
      al[mi] = *(const short8*)&Ql[wm + mi * 16 + l16][quad * 8];
    }
#pragma unroll
    for (int ni = 0; ni < 4; ni++) {
      short8 bh = *(const short8*)&Ch[wn + ni * 16 + l16][quad * 8];
      short8 bl = *(const short8*)&Cl[wn + ni * 16 + l16][quad * 8];
#pragma unroll
      for (int mi = 0; mi < 4; mi++) {
        acc[mi][ni] = __builtin_amdgcn_mfma_f32_16x16x32_bf16(ah[mi], bh, acc[mi][ni], 0, 0, 0);
        acc[mi][ni] = __builtin_amdgcn_mfma_f32_16x16x32_bf16(ah[mi], bl, acc[mi][ni], 0, 0, 0);
        acc[mi][ni] = __builtin_amdgcn_mfma_f32_16x16x32_bf16(al[mi], bh, acc[mi][ni], 0, 0, 0);
      }
    }
    __syncthreads();
  }
  unsigned long long memb = 0, fb = 0;
#pragma unroll
  for (int mi = 0; mi < 4; mi++)
#pragma unroll
    for (int ni = 0; ni < 4; ni++)
#pragma unroll
      for (int r = 0; r < 4; r++) {
        int e = (mi << 4) | (ni << 2) | r;
        float nqv = nqs[wm + mi * 16 + quad * 4 + r];
        float ncv = ncs[wn + ni * 16 + l16];
        float d2a = nqv + ncv - 2.f * acc[mi][ni][r];
        float eps = 4.0e-5f * (nqv + ncv) + 1.0e-6f;
        if (d2a < r2 - eps) memb |= 1ull << e;
        else if (d2a <= r2 + eps) fb |= 1ull << e;
      }
  while (fb) {
    int e = __builtin_ctzll(fb);
    fb &= fb - 1;
    int mi = e >> 4, ni = (e >> 2) & 3, r = e & 3;
    int qrow = q0 + wm + mi * 16 + quad * 4 + r;
    int ccol = c0 + wn + ni * 16 + l16;
    float a2 = 0.f;
    for (int k = 0; k < C; k++) {
      float d = F32[(size_t)qrow * C + k] - F32[(size_t)ccol * C + k];
      a2 = fmaf(d, d, a2);
    }
    if (a2 <= r2) memb |= 1ull << e;
  }
#pragma unroll
  for (int ni = 0; ni < 4; ni++) {
    int cl = wn + ni * 16 + l16;
    unsigned int w0b = 0, w1b = 0;
#pragma unroll
    for (int mi = 0; mi < 4; mi++)
#pragma unroll
      for (int r = 0; r < 4; r++)
        if (memb & (1ull << ((mi << 4) | (ni << 2) | r))) {
          unsigned int bitpos = ((mi & 1) << 4) | (quad << 2) | r;
          if (mi < 2) w0b |= 1u << bitpos;
          else w1b |= 1u << bitpos;
        }
    if (w0b) atomicOr(&tw[cl][(wm >> 5)], w0b);
    if (w1b) atomicOr(&tw[cl][(wm >> 5) + 1], w1b);
  }
  __syncthreads();
  {
    int row = tid >> 1, half = tid & 1;
    int wq = row >> 5, sb = row & 31;
    unsigned int lo = 0, hi = 0;
    for (int j = 0; j < 32; j++) {
      lo |= ((tw[half * 64 + j][wq] >> sb) & 1u) << j;
      hi |= ((tw[half * 64 + 32 + j][wq] >> sb) & 1u) << j;
    }
    mask[(size_t)(q0 + row) * 32 + (ct << 1) + half] =
        ((unsigned long long)hi << 32) | lo;
  }
  if (qt != ct) {
    int row = tid >> 1, word = tid & 1;
    unsigned long long v = (unsigned long long)tw[row][word * 2] |
                           ((unsigned long long)tw[row][word * 2 + 1] << 32);
    mask[(size_t)(c0 + row) * 32 + (qt << 1) + word] = v;
  }
}

// ---------------------------------------------------------------------------
// bf16 MFMA GEMM body (bf16 out). smem >= 20480 B.
// ---------------------------------------------------------------------------
__device__ void mfma_body(char* smem,
    const short* __restrict__ Ag, const short* __restrict__ Bg,
    const float* __restrict__ bias, __hip_bfloat16* __restrict__ Y,
    int lda, int ldw, int ldy, int K, int m0, int n0)
{
  short (*As)[40] = (short(*)[40])smem;
  short (*Bs)[40] = (short(*)[40])(smem + 10240);
  int tid = threadIdx.x;
  int wave = tid >> 6, lane = tid & 63;
  int quad = lane >> 4, l16 = lane & 15;
  int wm = (wave >> 1) << 6, wn = (wave & 1) << 6;
  f32x4 acc[4][4] = {};
  int srow = tid >> 2, sq = tid & 3;
  for (int k0 = 0; k0 < K; k0 += 32) {
#pragma unroll
    for (int h = 0; h < 2; h++) {
      int r = srow + (h << 6);
      uint4 va = *(const uint4*)&Ag[(size_t)(m0 + r) * lda + k0 + sq * 8];
      *(uint4*)&As[r][sq * 8] = va;
      uint4 vb = *(const uint4*)&Bg[(size_t)(n0 + r) * ldw + k0 + sq * 8];
      *(uint4*)&Bs[r][sq * 8] = vb;
    }
    __syncthreads();
    short8 a[4], b[4];
#pragma unroll
    for (int mi = 0; mi < 4; mi++)
      a[mi] = *(const short8*)&As[wm + mi * 16 + l16][quad * 8];
#pragma unroll
    for (int ni = 0; ni < 4; ni++)
      b[ni] = *(const short8*)&Bs[wn + ni * 16 + l16][quad * 8];
#pragma unroll
    for (int mi = 0; mi < 4; mi++)
#pragma unroll
      for (int ni = 0; ni < 4; ni++)
        acc[mi][ni] = __builtin_amdgcn_mfma_f32_16x16x32_bf16(
            a[mi], b[ni], acc[mi][ni], 0, 0, 0);
    __syncthreads();
  }
  float bn[4];
#pragma unroll
  for (int ni = 0; ni < 4; ni++) bn[ni] = bias[n0 + wn + ni * 16 + l16];
#pragma unroll
  for (int mi = 0; mi < 4; mi++)
#pragma unroll
    for (int ni = 0; ni < 4; ni++) {
      int n = n0 + wn + ni * 16 + l16;
#pragma unroll
      for (int r = 0; r < 4; r++) {
        int m = m0 + wm + mi * 16 + quad * 4 + r;
        float v = fmaxf(acc[mi][ni][r] + bn[ni], 0.f);
        Y[(size_t)m * ldy + n] = (__hip_bfloat16)v;
      }
    }
}

__global__ __launch_bounds__(256) void gemm_mfma_bf16(
    const __hip_bfloat16* __restrict__ A, int lda,
    const __hip_bfloat16* __restrict__ Wt, int ldw,
    const float* __restrict__ bias,
    __hip_bfloat16* __restrict__ Y, int ldy, int K)
{
  __shared__ __align__(16) char smem[20480];
  mfma_body(smem, (const short*)A, (const short*)Wt, bias, Y,
            lda, ldw, ldy, K, blockIdx.y << 7, blockIdx.x << 7);
}

struct GJobs {
  const short* A[3];
  const short* W[3];
  const float* bias[3];
  __hip_bfloat16* Y[3];
  int lda[3], ldw[3], ldy[3], N[3], K[3], xt[3], off[3];
};

__global__ __launch_bounds__(256) void gemm_mfma_multi(GJobs g)
{
  __shared__ __align__(16) char smem[20480];
  int bid = blockIdx.x;
  int j = 0;
#pragma unroll
  for (int t = 1; t < 3; t++)
    if (bid >= g.off[t]) j = t;
  int rel = bid - g.off[j];
  mfma_body(smem, g.A[j], g.W[j], g.bias[j], g.Y[j],
            g.lda[j], g.ldw[j], g.ldy[j], g.K[j],
            (rel / g.xt[j]) << 7, (rel % g.xt[j]) << 7);
}

// ---------------------------------------------------------------------------
// gather bf16 body (4 queries/block, one per wave; no __syncthreads).
// ---------------------------------------------------------------------------
__device__ void gather_bf16_body(char* smem, int blk,
    const unsigned long long* __restrict__ mask,
    const __hip_bfloat16* __restrict__ H, int CH,
    __hip_bfloat16* __restrict__ Yb, int ldy, int S)
{
  int (*idxl)[64] = (int(*)[64])smem;
  float (*wtab)[64] = (float(*)[64])(smem + 1024);
  int* scount = (int*)(smem + 2048);
  int tid = threadIdx.x;
  int wave = tid >> 6, lane = tid & 63;
  int q = ((blk & 7) << 11) + ((blk >> 3) << 2) + wave;
  int base = q & ~2047;
  if (lane < 32) {
    unsigned long long w = mask[(size_t)q * 32 + lane];
    int cnt = __popcll(w);
    int inc = cnt;
#pragma unroll
    for (int off = 1; off < 32; off <<= 1) {
      int o = __shfl_up(inc, off);
      if (lane >= off) inc += o;
    }
    if (lane == 31) scount[wave] = inc;
    int p = inc - cnt;
    while (w && p < 64) {
      int j = (lane << 6) + __builtin_ctzll(w);
      w &= w - 1;
      idxl[wave][p++] = j;
    }
  }
  int c = scount[wave];
  {
    int p = lane;
    int cnt = (p < c && p < S) ? ((S - 1 - p) / c + 1) : 0;
    wtab[wave][p] = (float)cnt / (float)S;
  }
  const unsigned short* Hs = (const unsigned short*)H;
  float acc[4] = {0.f, 0.f, 0.f, 0.f};
  int lim = c < S ? c : S;
#pragma unroll 4
  for (int s = 0; s < lim; s++) {
    float wv = wtab[wave][s];
    uint2 v = *(const uint2*)&Hs[(size_t)(base + idxl[wave][s]) * CH + lane * 4];
    acc[0] += wv * __uint_as_float(v.x << 16);
    acc[1] += wv * __uint_as_float(v.x & 0xffff0000u);
    acc[2] += wv * __uint_as_float(v.y << 16);
    acc[3] += wv * __uint_as_float(v.y & 0xffff0000u);
  }
  int n0 = lane * 4;
#pragma unroll
  for (int j = 0; j < 4; j++)
    Yb[(size_t)q * ldy + n0 + j] = (__hip_bfloat16)acc[j];
}

// ---------------------------------------------------------------------------
// MERGE B tail: fp1-l2 + fp2-l2 MFMA jobs (768 blocks) + gather3 (4096).
// (Both mfma and gather bodies are low-LDS here — coupling is benign.)
// ---------------------------------------------------------------------------
struct GJobs2 {
  const short* A[2];
  const short* W[2];
  const float* bias[2];
  __hip_bfloat16* Y[2];
  int lda[2], ldw[2], ldy[2], K[2], xt[2], off[2];
};

__global__ __launch_bounds__(256) void fused_tail(
    GJobs2 g, int goff,
    const unsigned long long* __restrict__ mask,
    const __hip_bfloat16* __restrict__ H, int CH,
    __hip_bfloat16* __restrict__ Yb, int ldy, int S)
{
  __shared__ __align__(16) char smem[20480];
  int bid = blockIdx.x;
  if (bid < goff) {
    int j = (bid >= g.off[1]) ? 1 : 0;
    int rel = bid - g.off[j];
    mfma_body(smem, g.A[j], g.W[j], g.bias[j], g.Y[j],
              g.lda[j], g.ldw[j], g.ldy[j], g.K[j],
              (rel / g.xt[j]) << 7, (rel % g.xt[j]) << 7);
    return;
  }
  gather_bf16_body(smem, bid - goff, mask, H, CH, Yb, ldy, S);
}

// ---------------------------------------------------------------------------
// gather2 fp32 (round-17 version, passing).
// ---------------------------------------------------------------------------
__global__ __launch_bounds__(256) void ball_gather4_f32(
    const unsigned long long* __restrict__ mask,
    const float* __restrict__ H, int CH,
    float* __restrict__ Yf, __hip_bfloat16* __restrict__ Yb,
    __hip_bfloat16* __restrict__ Ylo, float* __restrict__ nrm,
    int ldy, int S)
{
  int blk = blockIdx.x;
  int tid = threadIdx.x;
  int wave = tid >> 6, lane = tid & 63;
  int q = ((blk & 7) << 11) + ((blk >> 3) << 2) + wave;
  int base = q & ~2047;
  __shared__ int idxl[4][64];
  __shared__ float wtab[4][64];
  __shared__ int scount[4];
  if (lane < 32) {
    unsigned long long w = mask[(size_t)q * 32 + lane];
    int cnt = __popcll(w);
    int inc = cnt;
#pragma unroll
    for (int off = 1; off < 32; off <<= 1) {
      int o = __shfl_up(inc, off);
      if (lane >= off) inc += o;
    }
    if (lane == 31) scount[wave] = inc;
    int p = inc - cnt;
    while (w && p < 64) {
      int j = (lane << 6) + __builtin_ctzll(w);
      w &= w - 1;
      idxl[wave][p++] = j;
    }
  }
  int c = scount[wave];
  {
    int p = lane;
    int cnt = (p < c && p < S) ? ((S - 1 - p) / c + 1) : 0;
    wtab[wave][p] = (float)cnt / (float)S;
  }
  float acc0 = 0.f, acc1 = 0.f;
  int lim = c < S ? c : S;
#pragma unroll 4
  for (int s = 0; s < lim; s++) {
    float wv = wtab[wave][s];
    float2 v = *(const float2*)&H[(size_t)(base + idxl[wave][s]) * CH + lane * 2];
    acc0 += wv * v.x;
    acc1 += wv * v.y;
  }
  int n0 = lane * 2;
  if (Yf) *(float2*)&Yf[(size_t)q * ldy + n0] = make_float2(acc0, acc1);
  if (Yb) {
    Yb[(size_t)q * ldy + n0] = (__hip_bfloat16)acc0;
    Yb[(size_t)q * ldy + n0 + 1] = (__hip_bfloat16)acc1;
  }
  if (Ylo) {
    __hip_bfloat16 h0 = (__hip_bfloat16)acc0, h1 = (__hip_bfloat16)acc1;
    Ylo[(size_t)q * ldy + n0] = (__hip_bfloat16)(acc0 - (float)h0);
    Ylo[(size_t)q * ldy + n0 + 1] = (__hip_bfloat16)(acc1 - (float)h1);
  }
  if (nrm) {
    float nv = acc0 * acc0 + acc1 * acc1;
#pragma unroll
    for (int off = 32; off > 0; off >>= 1) nv += __shfl_down(nv, off);
    if (lane == 0) nrm[q] = nv;
  }
}

// ---------------------------------------------------------------------------
// fc2 + out head fused.
// ---------------------------------------------------------------------------
__global__ __launch_bounds__(256) void gemm_fc2_out(
    const __hip_bfloat16* __restrict__ A,
    const __hip_bfloat16* __restrict__ Wt,
    const float* __restrict__ bias,
    const float* __restrict__ wout,
    const float* __restrict__ bout,
    float* __restrict__ out)
{
  __shared__ __align__(16) short As[128][40];
  __shared__ __align__(16) short Bs[128][40];
  __shared__ float red[128][2];
  const int N = 128, K = 256, lda = 256, ldw = 256;
  int tid = threadIdx.x;
  int wave = tid >> 6, lane = tid & 63;
  int quad = lane >> 4, l16 = lane & 15;
  int m0 = blockIdx.y << 7;
  int wm = (wave >> 1) << 6, wn = (wave & 1) << 6;
  f32x4 acc[4][4] = {};
  const short* Ag = (const short*)A;
  const short* Bg = (const short*)Wt;
  int srow = tid >> 2, sq = tid & 3;
  for (int k0 = 0; k0 < K; k0 += 32) {
#pragma unroll
    for (int h = 0; h < 2; h++) {
      int r = srow + (h << 6);
      uint4 va = *(const uint4*)&Ag[(size_t)(m0 + r) * lda + k0 + sq * 8];
      *(uint4*)&As[r][sq * 8] = va;
      uint4 vb = *(const uint4*)&Bg[(size_t)(r % N) * ldw + k0 + sq * 8];
      *(uint4*)&Bs[r][sq * 8] = vb;
    }
    __syncthreads();
    short8 a[4], b[4];
#pragma unroll
    for (int mi = 0; mi < 4; mi++)
      a[mi] = *(const short8*)&As[wm + mi * 16 + l16][quad * 8];
#pragma unroll
    for (int ni = 0; ni < 4; ni++)
      b[ni] = *(const short8*)&Bs[wn + ni * 16 + l16][quad * 8];
#pragma unroll
    for (int mi = 0; mi < 4; mi++)
#pragma unroll
      for (int ni = 0; ni < 4; ni++)
        acc[mi][ni] = __builtin_amdgcn_mfma_f32_16x16x32_bf16(
            a[mi], b[ni], acc[mi][ni], 0, 0, 0);
    __syncthreads();
  }
  float bn[4], wo[4];
#pragma unroll
  for (int ni = 0; ni < 4; ni++) {
    int n = wn + ni * 16 + l16;
    bn[ni] = bias[n];
    wo[ni] = wout[n];
  }
  float sacc[4][4];
#pragma unroll
  for (int mi = 0; mi < 4; mi++)
#pragma unroll
    for (int r = 0; r < 4; r++) {
      float s = 0.f;
#pragma unroll
      for (int ni = 0; ni < 4; ni++)
        s += fmaxf(acc[mi][ni][r] + bn[ni], 0.f) * wo[ni];
      sacc[mi][r] = s;
    }
#pragma unroll
  for (int off = 1; off < 16; off <<= 1)
#pragma unroll
    for (int mi = 0; mi < 4; mi++)
#pragma unroll
      for (int r = 0; r < 4; r++)
        sacc[mi][r] += __shfl_xor(sacc[mi][r], off);
  int wp = wave & 1;
  if (l16 == 0) {
#pragma unroll
    for (int mi = 0; mi < 4; mi++)
#pragma unroll
      for (int r = 0; r < 4; r++)
        red[wm + mi * 16 + quad * 4 + r][wp] = sacc[mi][r];
  }
  __syncthreads();
  if (tid < 128) {
    float s = red[tid][0] + red[tid][1] + bout[0];
    out[(size_t)(m0 + tid)] = 1.f / (1.f + expf(-s));
  }
}

// ---------------------------------------------------------------------------
// SA1 KNN v9 (passing — bit-identical selection).
// ---------------------------------------------------------------------------
__global__ __launch_bounds__(256) void knn_mean4(
    const float* __restrict__ X,
    const float* __restrict__ G1,
    float* __restrict__ X1,
    __hip_bfloat16* __restrict__ X1b,
    __hip_bfloat16* __restrict__ X1lo,
    float* __restrict__ nrmX1)
{
  int blk = blockIdx.x;
  int qb = ((blk & 7) << 11) + ((blk >> 3) << 2);
  int base = qb & ~2047;
  int tid = threadIdx.x;
  int wave = tid >> 6, lane = tid & 63;
  __shared__ unsigned long long lmins[4][256];
  __shared__ unsigned long long qmins[4][64];
  __shared__ unsigned long long thr[4];
  __shared__ unsigned long long surv[4][256];
  __shared__ int scnt[4];
  __shared__ int selidx[4][32];
  if (tid < 4) scnt[tid] = 0;
  float xj[8], yj[8];
#pragma unroll
  for (int u = 0; u < 8; u++) {
    int j = (u << 8) + tid;
    float2 c = *(const float2*)&X[(size_t)(base + j) * 2];
    xj[u] = c.x;
    yj[u] = c.y;
  }
  unsigned long long key[4][8];
#pragma unroll
  for (int g = 0; g < 4; g++) {
    float qx = X[(size_t)(qb + g) * 2];
    float qy = X[(size_t)(qb + g) * 2 + 1];
    unsigned long long lm = ~0ull;
#pragma unroll
    for (int u = 0; u < 8; u++) {
      float dx = xj[u] - qx;
      float dy = yj[u] - qy;
      float d2 = dx * dx + dy * dy;
      key[g][u] = ((unsigned long long)__float_as_uint(d2) << 32) |
                  (unsigned)((u << 8) + tid);
      lm = umin64(lm, key[g][u]);
    }
    lmins[g][tid] = lm;
  }
  __syncthreads();
  {
    int g = wave;
    unsigned long long qm =
        umin64(umin64(lmins[g][lane], lmins[g][lane + 64]),
               umin64(lmins[g][lane + 128], lmins[g][lane + 192]));
    qmins[g][lane] = qm;
    int rank = 0;
    for (int i = 0; i < 64; i++) rank += (qmins[g][i] < qm);
    if (rank == 31) thr[g] = qm;
  }
  __syncthreads();
#pragma unroll
  for (int g = 0; g < 4; g++) {
    unsigned long long T = thr[g];
#pragma unroll
    for (int u = 0; u < 8; u++) {
      if (key[g][u] <= T) {
        int p = atomicAdd(&scnt[g], 1);
        if (p < 256) surv[g][p] = key[g][u];
      }
    }
  }
  __syncthreads();
  int ovf[4] = {scnt[0], scnt[1], scnt[2], scnt[3]};
  {
    int g = wave;
    int s = ovf[g];
    if (s <= 256) {
      for (int i = lane; i < s; i += 64) {
        unsigned long long c = surv[g][i];
        int r = 0;
        for (int j2 = 0; j2 < s; j2++) r += (surv[g][j2] < c);
        if (r < 32) selidx[g][r] = (int)(c & 0xffffffffULL);
      }
    }
  }
  if (ovf[0] > 256 || ovf[1] > 256 || ovf[2] > 256 || ovf[3] > 256) {
    unsigned long long* ob = &lmins[0][0];
    for (int g = 0; g < 4; g++) {
      if (ovf[g] <= 256) continue;
      __syncthreads();
      if (tid == 0) scnt[g] = 0;
      __syncthreads();
      unsigned long long T = thr[g];
#pragma unroll
      for (int u = 0; u < 8; u++) {
        if (key[g][u] <= T) {
          int p = atomicAdd(&scnt[g], 1);
          ob[p] = key[g][u];
        }
      }
      __syncthreads();
      int s2 = scnt[g];
      for (int i = tid; i < s2; i += 256) {
        unsigned long long c = ob[i];
        int r = 0;
        for (int j2 = 0; j2 < s2; j2++) r += (ob[j2] < c);
        if (r < 32) selidx[g][r] = (int)(c & 0xffffffffULL);
      }
    }
    __syncthreads();
  }
  {
    int g = wave;
    float acc = 0.f;
#pragma unroll 8
    for (int sI = 0; sI < 32; sI++)
      acc += G1[(size_t)(base + selidx[g][sI]) * 64 + lane];
    float v = acc * (1.0f / 32.0f);
    int q = qb + g;
    X1[(size_t)q * 64 + lane] = v;
    __hip_bfloat16 hi = (__hip_bfloat16)v;
    X1b[(size_t)q * 64 + lane] = hi;
    X1lo[(size_t)q * 64 + lane] = (__hip_bfloat16)(v - (float)hi);
    float nv = v * v;
#pragma unroll
    for (int off = 32; off > 0; off >>= 1) nv += __shfl_down(nv, off);
    if (lane == 0) nrmX1[q] = nv;
  }
}

// ---------------------------------------------------------------------------
extern "C" void kernel_launch(void* const* d_in, const int* in_sizes, int n_in,
                              void* d_out, int out_size, void* d_ws,
                              size_t ws_size, hipStream_t stream)
{
  const float* x      = (const float*)d_in[0];
  const float* sa1_w0 = (const float*)d_in[1];
  const float* sa1_b0 = (const float*)d_in[2];
  const float* sa1_w1 = (const float*)d_in[3];
  const float* sa1_b1 = (const float*)d_in[4];
  const float* sa2_w0 = (const float*)d_in[5];
  const float* sa2_b0 = (const float*)d_in[6];
  const float* sa2_w1 = (const float*)d_in[7];
  const float* sa2_b1 = (const float*)d_in[8];
  const float* sa3_w0 = (const float*)d_in[9];
  const float* sa3_b0 = (const float*)d_in[10];
  const float* sa3_w1 = (const float*)d_in[11];
  const float* sa3_b1 = (const float*)d_in[12];
  const float* fp1_w0 = (const float*)d_in[13];
  const float* fp1_b0 = (const float*)d_in[14];
  const float* fp1_w1 = (const float*)d_in[15];
  const float* fp1_b1 = (const float*)d_in[16];
  const float* fp2_w0 = (const float*)d_in[17];
  const float* fp2_b0 = (const float*)d_in[18];
  const float* fp2_w1 = (const float*)d_in[19];
  const float* fp2_b1 = (const float*)d_in[20];
  const float* fc1_w  = (const float*)d_in[21];
  const float* fc1_b  = (const float*)d_in[22];
  const float* fc2_w  = (const float*)d_in[23];
  const float* fc2_b  = (const float*)d_in[24];
  const float* out_w  = (const float*)d_in[25];
  const float* out_b  = (const float*)d_in[26];
  float* out = (float*)d_out;

  const size_t M = M_ROWS;
  float* ws = (float*)d_ws;
  float* G1  = ws + M * 256;
  float* X1  = ws + M * 320;
  float* X2  = ws + M * 384;
  float* H2  = ws + M * 512;
  __hip_bfloat16* H3b16 = (__hip_bfloat16*)(ws + M * 640);
  unsigned long long* MASK = (unsigned long long*)(ws + M * 896);
  __hip_bfloat16* X1b = (__hip_bfloat16*)(ws + M * 960);
  __hip_bfloat16* X2b = (__hip_bfloat16*)(ws + M * 992);
  __hip_bfloat16* TB0 = (__hip_bfloat16*)(ws + M * 1056);
  __hip_bfloat16* TB1 = (__hip_bfloat16*)(ws + M * 1184);
  __hip_bfloat16* TB2 = (__hip_bfloat16*)(ws + M * 1440);
  __hip_bfloat16* G   = (__hip_bfloat16*)(ws + M * 1568);
  __hip_bfloat16* H3b = (__hip_bfloat16*)(ws + M * 2080);
  __hip_bfloat16* WB  = (__hip_bfloat16*)(ws + M * 2208);
  __hip_bfloat16* X1lo = (__hip_bfloat16*)(ws + M * 2240);
  __hip_bfloat16* X2lo = (__hip_bfloat16*)(ws + M * 2272);
  float* nrmX1 = ws + M * 2336;
  float* nrmX2 = ws + M * 2337;
  if (ws_size < (size_t)M * 2340 * sizeof(float)) return;
  __hip_bfloat16* w_sa3_0 = WB;
  __hip_bfloat16* w_sa3_1 = w_sa3_0 + 32768;
  __hip_bfloat16* w_fp1_0 = w_sa3_1 + 65536;
  __hip_bfloat16* w_fp1_1 = w_fp1_0 + 65536;
  __hip_bfloat16* w_fp2_0 = w_fp1_1 + 262144;
  __hip_bfloat16* w_fp2_1 = w_fp2_0 + 16384;
  __hip_bfloat16* w_fc1   = w_fp2_1 + 65536;
  __hip_bfloat16* w_fc2   = w_fc1 + 262144;

  dim3 blk(256);
  TJobs jb;
  const float* srcs[8] = {sa3_w0, sa3_w1, fp1_w0, fp1_w1, fp2_w0, fp2_w1, fc1_w, fc2_w};
  __hip_bfloat16* dsts[8] = {w_sa3_0, w_sa3_1, w_fp1_0, w_fp1_1, w_fp2_0, w_fp2_1, w_fc1, w_fc2};
  int Ks[8] = {128, 256, 128, 512, 64, 256, 1024, 256};
  int Ns[8] = {256, 256, 512, 512, 256, 256, 256, 128};
  int off = 0;
  for (int i = 0; i < 8; i++) {
    jb.W[i] = srcs[i]; jb.Wt[i] = dsts[i];
    jb.K[i] = Ks[i]; jb.N[i] = Ns[i];
    jb.bx[i] = Ns[i] >> 5;
    jb.off[i] = off;
    off += (Ns[i] >> 5) * (Ks[i] >> 5);
  }
  prologue_kernel<<<off + 256, blk, 0, stream>>>(jb, off, x, sa1_w0, sa1_b0,
                                                 sa1_w1, sa1_b1, G1);
  knn_mean4<<<4096, 256, 0, stream>>>(x, G1, X1, X1b, X1lo, nrmX1);
  // SA2 standalone + ball64 standalone (round-17 operating point).
  sa2_fused<<<256, blk, 0, stream>>>(X1, sa2_w0, sa2_b0, sa2_w1, sa2_b1, H2);
  ball_mask_mfma<64><<<dim3(136, 8), blk, 0, stream>>>(X1, X1b, X1lo, nrmX1, MASK, 0.2f * 0.2f);
  ball_gather4_f32<<<4096, blk, 0, stream>>>(MASK, H2, 128, X2, X2b, X2lo, nrmX2, 128, 32);
  // ball128, then g1 triple, then sa3-l2.
  ball_mask_mfma<128><<<dim3(136, 8), blk, 0, stream>>>(X2, X2b, X2lo, nrmX2, MASK, 0.4f * 0.4f);
  {
    GJobs g1;
    g1.A[0] = (const short*)X2b; g1.W[0] = (const short*)w_sa3_0; g1.bias[0] = sa3_b0;
    g1.Y[0] = TB0; g1.lda[0] = 128; g1.ldw[0] = 128; g1.ldy[0] = 256; g1.N[0] = 256; g1.K[0] = 128;
    g1.A[1] = (const short*)X2b; g1.W[1] = (const short*)w_fp1_0; g1.bias[1] = fp1_b0;
    g1.Y[1] = TB1; g1.lda[1] = 128; g1.ldw[1] = 128; g1.ldy[1] = 512; g1.N[1] = 512; g1.K[1] = 128;
    g1.A[2] = (const short*)X1b; g1.W[2] = (const short*)w_fp2_0; g1.bias[2] = fp2_b0;
    g1.Y[2] = TB2; g1.lda[2] = 64; g1.ldw[2] = 64; g1.ldy[2] = 256; g1.N[2] = 256; g1.K[2] = 64;
    int tot1 = 0;
    for (int i = 0; i < 3; i++) {
      g1.xt[i] = g1.N[i] >> 7;
      g1.off[i] = tot1;
      tot1 += g1.xt[i] * 128;
    }
    gemm_mfma_multi<<<tot1, blk, 0, stream>>>(g1);
  }
  gemm_mfma_bf16<<<dim3(2, 128), blk, 0, stream>>>(TB0, 256, w_sa3_1, 256,
                                                   sa3_b1, H3b16, 256, 256);
  // MERGE B: fp1-l2 + fp2-l2 + gather3 in one dispatch (low-LDS bodies).
  {
    GJobs2 g2;
    g2.A[0] = (const short*)TB1; g2.W[0] = (const short*)w_fp1_1; g2.bias[0] = fp1_b1;
    g2.Y[0] = G + 256; g2.lda[0] = 512; g2.ldw[0] = 512; g2.ldy[0] = 1024; g2.K[0] = 512;
    g2.xt[0] = 4; g2.off[0] = 0;                 // 512 blocks
    g2.A[1] = (const short*)TB2; g2.W[1] = (const short*)w_fp2_1; g2.bias[1] = fp2_b1;
    g2.Y[1] = G; g2.lda[1] = 256; g2.ldw[1] = 256; g2.ldy[1] = 1024; g2.K[1] = 256;
    g2.xt[1] = 2; g2.off[1] = 512;               // 256 blocks
    int goff = 768;
    fused_tail<<<goff + 4096, blk, 0, stream>>>(g2, goff, MASK, H3b16, 256,
                                                G + 768, 1024, 64);
  }
  // Head: fc1 (bf16), then fc2+out fused.
  gemm_mfma_bf16<<<dim3(2, 128), blk, 0, stream>>>(G, 1024, w_fc1, 1024,
                                                   fc1_b, H3b, 256, 1024);
  gemm_fc2_out<<<dim3(1, 128), blk, 0, stream>>>(H3b, w_fc2, fc2_b, out_w, out_b, out);
}

// Round 20
// 338.610 us; speedup vs baseline: 1.0749x; 1.0341x over previous
//
#include <hip/hip_runtime.h>
#include <hip/hip_bf16.h>
#include <cstdint>

#define M_ROWS 16384

typedef __attribute__((ext_vector_type(8))) short short8;
typedef __attribute__((ext_vector_type(4))) float f32x4;

__device__ __forceinline__ unsigned long long umin64(unsigned long long a,
                                                     unsigned long long b) {
  return a < b ? a : b;
}

// ---------------------------------------------------------------------------
// PROLOGUE: 8 weight transposes + SA1 fused MLP in one dispatch.
// ---------------------------------------------------------------------------
struct TJobs {
  const float* W[8];
  __hip_bfloat16* Wt[8];
  int K[8], N[8], bx[8], off[8];
};

__global__ __launch_bounds__(256) void prologue_kernel(
    TJobs jb, int toff,
    const float* __restrict__ x,
    const float* __restrict__ w0,
    const float* __restrict__ b0,
    const float* __restrict__ w1,
    const float* __restrict__ b1,
    float* __restrict__ G1)
{
  __shared__ float tile[32][33];
  __shared__ __align__(16) float Ts[64][68];
  __shared__ __align__(16) float Ws[64][68];
  __shared__ float xs[64][2];
  __shared__ float w0s[2][64];
  __shared__ float b0s[64];
  int bid = blockIdx.x;
  int tid = threadIdx.x;
  if (bid < toff) {
    int j = 0;
#pragma unroll
    for (int t = 1; t < 8; t++)
      if (bid >= jb.off[t]) j = t;
    int rel = bid - jb.off[j];
    int K = jb.K[j], N = jb.N[j];
    const float* W = jb.W[j];
    __hip_bfloat16* Wt = jb.Wt[j];
    int n0 = (rel % jb.bx[j]) << 5, k0 = (rel / jb.bx[j]) << 5;
    int c = tid & 31, i0 = tid >> 5;
#pragma unroll
    for (int p = 0; p < 4; p++) {
      int i = i0 + p * 8;
      tile[i][c] = W[(size_t)(k0 + i) * N + n0 + c];
    }
    __syncthreads();
#pragma unroll
    for (int p = 0; p < 4; p++) {
      int r = i0 + p * 8;
      Wt[(size_t)(n0 + r) * K + k0 + c] = (__hip_bfloat16)tile[c][r];
    }
    return;
  }
  int m0 = (bid - toff) << 6;
  if (tid < 128) {
    ((float*)xs)[tid] = x[(size_t)m0 * 2 + tid];
  } else if (tid < 192) {
    int n = tid - 128;
    w0s[0][n] = w0[n];
    b0s[n] = b0[n];
  } else {
    int n = tid - 192;
    w0s[1][n] = w0[64 + n];
  }
#pragma unroll
  for (int i = 0; i < 16; i++) {
    int idx = tid + (i << 8);
    int k = idx >> 6, n = idx & 63;
    Ws[k][n] = w1[(size_t)k * 64 + n];
  }
  __syncthreads();
#pragma unroll
  for (int i = 0; i < 16; i++) {
    int idx = tid + (i << 8);
    int m = idx >> 6, n = idx & 63;
    float acc = 0.f;
    acc += xs[m][0] * w0s[0][n];
    acc += xs[m][1] * w0s[1][n];
    Ts[n][m] = fmaxf(acc + b0s[n], 0.f);
  }
  __syncthreads();
  int tx = tid & 15, ty = tid >> 4;
  float acc[4][4] = {};
  for (int k = 0; k < 64; k++) {
    float4 a4 = *(const float4*)&Ts[k][ty << 2];
    float4 b4 = *(const float4*)&Ws[k][tx << 2];
    float av[4] = {a4.x, a4.y, a4.z, a4.w};
    float bv[4] = {b4.x, b4.y, b4.z, b4.w};
#pragma unroll
    for (int i = 0; i < 4; i++)
#pragma unroll
      for (int j = 0; j < 4; j++)
        acc[i][j] += av[i] * bv[j];
  }
  float4 bb = *(const float4*)&b1[tx << 2];
  float bv[4] = {bb.x, bb.y, bb.z, bb.w};
#pragma unroll
  for (int i = 0; i < 4; i++) {
    int m = m0 + (ty << 2) + i;
    float4 o;
    o.x = fmaxf(acc[i][0] + bv[0], 0.f);
    o.y = fmaxf(acc[i][1] + bv[1], 0.f);
    o.z = fmaxf(acc[i][2] + bv[2], 0.f);
    o.w = fmaxf(acc[i][3] + bv[3], 0.f);
    *(float4*)&G1[(size_t)m * 64 + (tx << 2)] = o;
  }
}

// ---------------------------------------------------------------------------
// SA2 fused (round-16/17 version, passing; H2 bit-identical).
// ---------------------------------------------------------------------------
__global__ __launch_bounds__(256) void sa2_fused(
    const float* __restrict__ X1,
    const float* __restrict__ w0,
    const float* __restrict__ b0,
    const float* __restrict__ w1,
    const float* __restrict__ b1,
    float* __restrict__ H2)
{
  __shared__ __align__(16) float Ts[128][68];
  __shared__ __align__(16) float Bs[16][132];
  __shared__ __align__(16) float Xs[16][68];
  int tid = threadIdx.x;
  int tx = tid & 15, ty = tid >> 4;
  int m0 = blockIdx.x << 6;
  float acc1[4][8] = {};
  for (int k0 = 0; k0 < 64; k0 += 16) {
#pragma unroll
    for (int i = 0; i < 4; i++) {
      int idx = tid + (i << 8);
      int m = idx >> 4, k = idx & 15;
      Xs[k][m] = X1[(size_t)(m0 + m) * 64 + k0 + k];
    }
#pragma unroll
    for (int i = 0; i < 8; i++) {
      int idx = tid + (i << 8);
      int n = idx & 127, k = idx >> 7;
      Bs[k][n] = w0[(size_t)(k0 + k) * 128 + n];
    }
    __syncthreads();
#pragma unroll
    for (int k = 0; k < 16; k++) {
      float av[4], bv[8];
#pragma unroll
      for (int i = 0; i < 4; i++) av[i] = Xs[k][ty * 4 + i];
#pragma unroll
      for (int j = 0; j < 8; j++) bv[j] = Bs[k][tx * 8 + j];
#pragma unroll
      for (int i = 0; i < 4; i++)
#pragma unroll
        for (int j = 0; j < 8; j++)
          acc1[i][j] += av[i] * bv[j];
    }
    __syncthreads();
  }
#pragma unroll
  for (int j = 0; j < 8; j++) {
    float bbv = b0[tx * 8 + j];
#pragma unroll
    for (int i = 0; i < 4; i++)
      Ts[tx * 8 + j][ty * 4 + i] = fmaxf(acc1[i][j] + bbv, 0.f);
  }
  __syncthreads();
  float acc2[4][8] = {};
  for (int k0 = 0; k0 < 128; k0 += 16) {
#pragma unroll
    for (int i = 0; i < 8; i++) {
      int idx = tid + (i << 8);
      int n = idx & 127, k = idx >> 7;
      Bs[k][n] = w1[(size_t)(k0 + k) * 128 + n];
    }
    __syncthreads();
#pragma unroll
    for (int k = 0; k < 16; k++) {
      float av[4], bv[8];
#pragma unroll
      for (int i = 0; i < 4; i++) av[i] = Ts[k0 + k][ty * 4 + i];
#pragma unroll
      for (int j = 0; j < 8; j++) bv[j] = Bs[k][tx * 8 + j];
#pragma unroll
      for (int i = 0; i < 4; i++)
#pragma unroll
        for (int j = 0; j < 8; j++)
          acc2[i][j] += av[i] * bv[j];
    }
    __syncthreads();
  }
#pragma unroll
  for (int i = 0; i < 4; i++) {
    int m = m0 + ty * 4 + i;
#pragma unroll
    for (int j = 0; j < 8; j++) {
      int n = tx * 8 + j;
      H2[(size_t)m * 128 + n] = fmaxf(acc2[i][j] + b1[n], 0.f);
    }
  }
}

// ---------------------------------------------------------------------------
// bf16 MFMA GEMM (single-job; used for fc1).
// ---------------------------------------------------------------------------
template <bool OUT_BF16>
__global__ __launch_bounds__(256) void gemm_mfma(
    const __hip_bfloat16* __restrict__ A, int lda,
    const __hip_bfloat16* __restrict__ Wt, int ldw,
    const float* __restrict__ bias,
    void* __restrict__ Y, int ldy, int N, int K)
{
  __shared__ __align__(16) short As[128][40];
  __shared__ __align__(16) short Bs[128][40];
  int tid = threadIdx.x;
  int wave = tid >> 6, lane = tid & 63;
  int quad = lane >> 4, l16 = lane & 15;
  int m0 = blockIdx.y << 7, n0 = blockIdx.x << 7;
  int wm = (wave >> 1) << 6, wn = (wave & 1) << 6;
  f32x4 acc[4][4] = {};
  const short* Ag = (const short*)A;
  const short* Bg = (const short*)Wt;
  int srow = tid >> 2, sq = tid & 3;
  for (int k0 = 0; k0 < K; k0 += 32) {
#pragma unroll
    for (int h = 0; h < 2; h++) {
      int r = srow + (h << 6);
      uint4 va = *(const uint4*)&Ag[(size_t)(m0 + r) * lda + k0 + sq * 8];
      *(uint4*)&As[r][sq * 8] = va;
      uint4 vb = *(const uint4*)&Bg[(size_t)(n0 + r) * ldw + k0 + sq * 8];
      *(uint4*)&Bs[r][sq * 8] = vb;
    }
    __syncthreads();
    short8 a[4], b[4];
#pragma unroll
    for (int mi = 0; mi < 4; mi++)
      a[mi] = *(const short8*)&As[wm + mi * 16 + l16][quad * 8];
#pragma unroll
    for (int ni = 0; ni < 4; ni++)
      b[ni] = *(const short8*)&Bs[wn + ni * 16 + l16][quad * 8];
#pragma unroll
    for (int mi = 0; mi < 4; mi++)
#pragma unroll
      for (int ni = 0; ni < 4; ni++)
        acc[mi][ni] = __builtin_amdgcn_mfma_f32_16x16x32_bf16(
            a[mi], b[ni], acc[mi][ni], 0, 0, 0);
    __syncthreads();
  }
  float bn[4];
#pragma unroll
  for (int ni = 0; ni < 4; ni++) bn[ni] = bias[n0 + wn + ni * 16 + l16];
#pragma unroll
  for (int mi = 0; mi < 4; mi++)
#pragma unroll
    for (int ni = 0; ni < 4; ni++) {
      int n = n0 + wn + ni * 16 + l16;
#pragma unroll
      for (int r = 0; r < 4; r++) {
        int m = m0 + wm + mi * 16 + quad * 4 + r;
        float v = fmaxf(acc[mi][ni][r] + bn[ni], 0.f);
        if (OUT_BF16)
          ((__hip_bfloat16*)Y)[(size_t)m * ldy + n] = (__hip_bfloat16)v;
        else
          ((float*)Y)[(size_t)m * ldy + n] = v;
      }
    }
}

// ---------------------------------------------------------------------------
// Multi-job bf16 MFMA GEMM.
// ---------------------------------------------------------------------------
struct GJobs {
  const short* A[3];
  const short* W[3];
  const float* bias[3];
  __hip_bfloat16* Y[3];
  int lda[3], ldw[3], ldy[3], N[3], K[3], xt[3], off[3];
};

__global__ __launch_bounds__(256) void gemm_mfma_multi(GJobs g)
{
  __shared__ __align__(16) short As[128][40];
  __shared__ __align__(16) short Bs[128][40];
  int bid = blockIdx.x;
  int j = 0;
#pragma unroll
  for (int t = 1; t < 3; t++)
    if (bid >= g.off[t]) j = t;
  int rel = bid - g.off[j];
  int xt = g.xt[j];
  int m0 = (rel / xt) << 7, n0 = (rel % xt) << 7;
  int lda = g.lda[j], ldw = g.ldw[j], ldy = g.ldy[j], K = g.K[j];
  const short* Ag = g.A[j];
  const short* Bg = g.W[j];
  const float* bias = g.bias[j];
  __hip_bfloat16* Y = g.Y[j];

  int tid = threadIdx.x;
  int wave = tid >> 6, lane = tid & 63;
  int quad = lane >> 4, l16 = lane & 15;
  int wm = (wave >> 1) << 6, wn = (wave & 1) << 6;
  f32x4 acc[4][4] = {};
  int srow = tid >> 2, sq = tid & 3;
  for (int k0 = 0; k0 < K; k0 += 32) {
#pragma unroll
    for (int h = 0; h < 2; h++) {
      int r = srow + (h << 6);
      uint4 va = *(const uint4*)&Ag[(size_t)(m0 + r) * lda + k0 + sq * 8];
      *(uint4*)&As[r][sq * 8] = va;
      uint4 vb = *(const uint4*)&Bg[(size_t)(n0 + r) * ldw + k0 + sq * 8];
      *(uint4*)&Bs[r][sq * 8] = vb;
    }
    __syncthreads();
    short8 a[4], b[4];
#pragma unroll
    for (int mi = 0; mi < 4; mi++)
      a[mi] = *(const short8*)&As[wm + mi * 16 + l16][quad * 8];
#pragma unroll
    for (int ni = 0; ni < 4; ni++)
      b[ni] = *(const short8*)&Bs[wn + ni * 16 + l16][quad * 8];
#pragma unroll
    for (int mi = 0; mi < 4; mi++)
#pragma unroll
      for (int ni = 0; ni < 4; ni++)
        acc[mi][ni] = __builtin_amdgcn_mfma_f32_16x16x32_bf16(
            a[mi], b[ni], acc[mi][ni], 0, 0, 0);
    __syncthreads();
  }
  float bn[4];
#pragma unroll
  for (int ni = 0; ni < 4; ni++) bn[ni] = bias[n0 + wn + ni * 16 + l16];
#pragma unroll
  for (int mi = 0; mi < 4; mi++)
#pragma unroll
    for (int ni = 0; ni < 4; ni++) {
      int n = n0 + wn + ni * 16 + l16;
#pragma unroll
      for (int r = 0; r < 4; r++) {
        int m = m0 + wm + mi * 16 + quad * 4 + r;
        float v = fmaxf(acc[mi][ni][r] + bn[ni], 0.f);
        Y[(size_t)m * ldy + n] = (__hip_bfloat16)v;
      }
    }
}

// ---------------------------------------------------------------------------
// fc2 + out head fused.
// ---------------------------------------------------------------------------
__global__ __launch_bounds__(256) void gemm_fc2_out(
    const __hip_bfloat16* __restrict__ A,
    const __hip_bfloat16* __restrict__ Wt,
    const float* __restrict__ bias,
    const float* __restrict__ wout,
    const float* __restrict__ bout,
    float* __restrict__ out)
{
  __shared__ __align__(16) short As[128][40];
  __shared__ __align__(16) short Bs[128][40];
  __shared__ float red[128][2];
  const int N = 128, K = 256, lda = 256, ldw = 256;
  int tid = threadIdx.x;
  int wave = tid >> 6, lane = tid & 63;
  int quad = lane >> 4, l16 = lane & 15;
  int m0 = blockIdx.y << 7;
  int wm = (wave >> 1) << 6, wn = (wave & 1) << 6;
  f32x4 acc[4][4] = {};
  const short* Ag = (const short*)A;
  const short* Bg = (const short*)Wt;
  int srow = tid >> 2, sq = tid & 3;
  for (int k0 = 0; k0 < K; k0 += 32) {
#pragma unroll
    for (int h = 0; h < 2; h++) {
      int r = srow + (h << 6);
      uint4 va = *(const uint4*)&Ag[(size_t)(m0 + r) * lda + k0 + sq * 8];
      *(uint4*)&As[r][sq * 8] = va;
      uint4 vb = *(const uint4*)&Bg[(size_t)(r % N) * ldw + k0 + sq * 8];
      *(uint4*)&Bs[r][sq * 8] = vb;
    }
    __syncthreads();
    short8 a[4], b[4];
#pragma unroll
    for (int mi = 0; mi < 4; mi++)
      a[mi] = *(const short8*)&As[wm + mi * 16 + l16][quad * 8];
#pragma unroll
    for (int ni = 0; ni < 4; ni++)
      b[ni] = *(const short8*)&Bs[wn + ni * 16 + l16][quad * 8];
#pragma unroll
    for (int mi = 0; mi < 4; mi++)
#pragma unroll
      for (int ni = 0; ni < 4; ni++)
        acc[mi][ni] = __builtin_amdgcn_mfma_f32_16x16x32_bf16(
            a[mi], b[ni], acc[mi][ni], 0, 0, 0);
    __syncthreads();
  }
  float bn[4], wo[4];
#pragma unroll
  for (int ni = 0; ni < 4; ni++) {
    int n = wn + ni * 16 + l16;
    bn[ni] = bias[n];
    wo[ni] = wout[n];
  }
  float sacc[4][4];
#pragma unroll
  for (int mi = 0; mi < 4; mi++)
#pragma unroll
    for (int r = 0; r < 4; r++) {
      float s = 0.f;
#pragma unroll
      for (int ni = 0; ni < 4; ni++)
        s += fmaxf(acc[mi][ni][r] + bn[ni], 0.f) * wo[ni];
      sacc[mi][r] = s;
    }
#pragma unroll
  for (int off = 1; off < 16; off <<= 1)
#pragma unroll
    for (int mi = 0; mi < 4; mi++)
#pragma unroll
      for (int r = 0; r < 4; r++)
        sacc[mi][r] += __shfl_xor(sacc[mi][r], off);
  int wp = wave & 1;
  if (l16 == 0) {
#pragma unroll
    for (int mi = 0; mi < 4; mi++)
#pragma unroll
      for (int r = 0; r < 4; r++)
        red[wm + mi * 16 + quad * 4 + r][wp] = sacc[mi][r];
  }
  __syncthreads();
  if (tid < 128) {
    float s = red[tid][0] + red[tid][1] + bout[0];
    out[(size_t)(m0 + tid)] = 1.f / (1.f + expf(-s));
  }
}

// ---------------------------------------------------------------------------
// SA1 KNN v9 (round-15..17 version, passing — bit-identical selection).
// ---------------------------------------------------------------------------
__global__ __launch_bounds__(256) void knn_mean4(
    const float* __restrict__ X,
    const float* __restrict__ G1,
    float* __restrict__ X1,
    __hip_bfloat16* __restrict__ X1b,
    __hip_bfloat16* __restrict__ X1lo,
    float* __restrict__ nrmX1)
{
  int blk = blockIdx.x;
  int qb = ((blk & 7) << 11) + ((blk >> 3) << 2);
  int base = qb & ~2047;
  int tid = threadIdx.x;
  int wave = tid >> 6, lane = tid & 63;
  __shared__ unsigned long long lmins[4][256];
  __shared__ unsigned long long qmins[4][64];
  __shared__ unsigned long long thr[4];
  __shared__ unsigned long long surv[4][256];
  __shared__ int scnt[4];
  __shared__ int selidx[4][32];
  if (tid < 4) scnt[tid] = 0;
  float xj[8], yj[8];
#pragma unroll
  for (int u = 0; u < 8; u++) {
    int j = (u << 8) + tid;
    float2 c = *(const float2*)&X[(size_t)(base + j) * 2];
    xj[u] = c.x;
    yj[u] = c.y;
  }
  unsigned long long key[4][8];
#pragma unroll
  for (int g = 0; g < 4; g++) {
    float qx = X[(size_t)(qb + g) * 2];
    float qy = X[(size_t)(qb + g) * 2 + 1];
    unsigned long long lm = ~0ull;
#pragma unroll
    for (int u = 0; u < 8; u++) {
      float dx = xj[u] - qx;
      float dy = yj[u] - qy;
      float d2 = dx * dx + dy * dy;
      key[g][u] = ((unsigned long long)__float_as_uint(d2) << 32) |
                  (unsigned)((u << 8) + tid);
      lm = umin64(lm, key[g][u]);
    }
    lmins[g][tid] = lm;
  }
  __syncthreads();
  {
    int g = wave;
    unsigned long long qm =
        umin64(umin64(lmins[g][lane], lmins[g][lane + 64]),
               umin64(lmins[g][lane + 128], lmins[g][lane + 192]));
    qmins[g][lane] = qm;
    int rank = 0;
    for (int i = 0; i < 64; i++) rank += (qmins[g][i] < qm);
    if (rank == 31) thr[g] = qm;
  }
  __syncthreads();
#pragma unroll
  for (int g = 0; g < 4; g++) {
    unsigned long long T = thr[g];
#pragma unroll
    for (int u = 0; u < 8; u++) {
      if (key[g][u] <= T) {
        int p = atomicAdd(&scnt[g], 1);
        if (p < 256) surv[g][p] = key[g][u];
      }
    }
  }
  __syncthreads();
  int ovf[4] = {scnt[0], scnt[1], scnt[2], scnt[3]};
  {
    int g = wave;
    int s = ovf[g];
    if (s <= 256) {
      for (int i = lane; i < s; i += 64) {
        unsigned long long c = surv[g][i];
        int r = 0;
        for (int j2 = 0; j2 < s; j2++) r += (surv[g][j2] < c);
        if (r < 32) selidx[g][r] = (int)(c & 0xffffffffULL);
      }
    }
  }
  if (ovf[0] > 256 || ovf[1] > 256 || ovf[2] > 256 || ovf[3] > 256) {
    unsigned long long* ob = &lmins[0][0];
    for (int g = 0; g < 4; g++) {
      if (ovf[g] <= 256) continue;
      __syncthreads();
      if (tid == 0) scnt[g] = 0;
      __syncthreads();
      unsigned long long T = thr[g];
#pragma unroll
      for (int u = 0; u < 8; u++) {
        if (key[g][u] <= T) {
          int p = atomicAdd(&scnt[g], 1);
          ob[p] = key[g][u];
        }
      }
      __syncthreads();
      int s2 = scnt[g];
      for (int i = tid; i < s2; i += 256) {
        unsigned long long c = ob[i];
        int r = 0;
        for (int j2 = 0; j2 < s2; j2++) r += (ob[j2] < c);
        if (r < 32) selidx[g][r] = (int)(c & 0xffffffffULL);
      }
    }
    __syncthreads();
  }
  {
    int g = wave;
    float acc = 0.f;
#pragma unroll 8
    for (int sI = 0; sI < 32; sI++)
      acc += G1[(size_t)(base + selidx[g][sI]) * 64 + lane];
    float v = acc * (1.0f / 32.0f);
    int q = qb + g;
    X1[(size_t)q * 64 + lane] = v;
    __hip_bfloat16 hi = (__hip_bfloat16)v;
    X1b[(size_t)q * 64 + lane] = hi;
    X1lo[(size_t)q * 64 + lane] = (__hip_bfloat16)(v - (float)hi);
    float nv = v * v;
#pragma unroll
    for (int off = 32; off > 0; off >>= 1) nv += __shfl_down(nv, off);
    if (lane == 0) nrmX1[q] = nv;
  }
}

// ---------------------------------------------------------------------------
// Ball-query pass 1 — split-bf16 MFMA gram + exact-decision guard band
// (round-12 version, passing; masks bit-identical).
// ---------------------------------------------------------------------------
template <int C>
__global__ __launch_bounds__(256) void ball_mask_mfma(
    const float* __restrict__ F32,
    const __hip_bfloat16* __restrict__ Fhi,
    const __hip_bfloat16* __restrict__ Flo,
    const float* __restrict__ nrm,
    unsigned long long* __restrict__ mask,
    float r2)
{
  __shared__ __align__(16) short Qh[128][40];
  __shared__ __align__(16) short Ql[128][40];
  __shared__ __align__(16) short Ch[128][40];
  __shared__ __align__(16) short Cl[128][40];
  __shared__ unsigned int tw[128][4];
  __shared__ float nqs[128], ncs[128];
  int tid = threadIdx.x;
  int p = blockIdx.x;
  int qt = 0;
  while (p >= 16 - qt) { p -= 16 - qt; qt++; }
  int ct = qt + p;
  int b0 = blockIdx.y << 11;
  int q0 = b0 + (qt << 7), c0 = b0 + (ct << 7);
  tw[tid >> 1][(tid & 1) * 2] = 0;
  tw[tid >> 1][(tid & 1) * 2 + 1] = 0;
  if (tid < 128) nqs[tid] = nrm[q0 + tid];
  else ncs[tid - 128] = nrm[c0 + tid - 128];

  int wave = tid >> 6, lane = tid & 63;
  int quad = lane >> 4, l16 = lane & 15;
  int wm = (wave >> 1) << 6, wn = (wave & 1) << 6;
  f32x4 acc[4][4] = {};
  const short* QH = (const short*)Fhi;
  const short* QL = (const short*)Flo;
  int srow = tid >> 2, sq = tid & 3;
  for (int k0 = 0; k0 < C; k0 += 32) {
#pragma unroll
    for (int h = 0; h < 2; h++) {
      int r = srow + (h << 6);
      *(uint4*)&Qh[r][sq * 8] = *(const uint4*)&QH[(size_t)(q0 + r) * C + k0 + sq * 8];
      *(uint4*)&Ql[r][sq * 8] = *(const uint4*)&QL[(size_t)(q0 + r) * C + k0 + sq * 8];
      *(uint4*)&Ch[r][sq * 8] = *(const uint4*)&QH[(size_t)(c0 + r) * C + k0 + sq * 8];
      *(uint4*)&Cl[r][sq * 8] = *(const uint4*)&QL[(size_t)(c0 + r) * C + k0 + sq * 8];
    }
    __syncthreads();
    short8 ah[4], al[4];
#pragma unroll
    for (int mi = 0; mi < 4; mi++) {
      ah[mi] = *(const short8*)&Qh[wm + mi * 16 + l16][quad * 8];
      al[mi] = *(const short8*)&Ql[wm + mi * 16 + l16][quad * 8];
    }
#pragma unroll
    for (int ni = 0; ni < 4; ni++) {
      short8 bh = *(const short8*)&Ch[wn + ni * 16 + l16][quad * 8];
      short8 bl = *(const short8*)&Cl[wn + ni * 16 + l16][quad * 8];
#pragma unroll
      for (int mi = 0; mi < 4; mi++) {
        acc[mi][ni] = __builtin_amdgcn_mfma_f32_16x16x32_bf16(ah[mi], bh, acc[mi][ni], 0, 0, 0);
        acc[mi][ni] = __builtin_amdgcn_mfma_f32_16x16x32_bf16(ah[mi], bl, acc[mi][ni], 0, 0, 0);
        acc[mi][ni] = __builtin_amdgcn_mfma_f32_16x16x32_bf16(al[mi], bh, acc[mi][ni], 0, 0, 0);
      }
    }
    __syncthreads();
  }
  unsigned long long memb = 0, fb = 0;
#pragma unroll
  for (int mi = 0; mi < 4; mi++)
#pragma unroll
    for (int ni = 0; ni < 4; ni++)
#pragma unroll
      for (int r = 0; r < 4; r++) {
        int e = (mi << 4) | (ni << 2) | r;
        float nqv = nqs[wm + mi * 16 + quad * 4 + r];
        float ncv = ncs[wn + ni * 16 + l16];
        float d2a = nqv + ncv - 2.f * acc[mi][ni][r];
        float eps = 4.0e-5f * (nqv + ncv) + 1.0e-6f;
        if (d2a < r2 - eps) memb |= 1ull << e;
        else if (d2a <= r2 + eps) fb |= 1ull << e;
      }
  while (fb) {
    int e = __builtin_ctzll(fb);
    fb &= fb - 1;
    int mi = e >> 4, ni = (e >> 2) & 3, r = e & 3;
    int qrow = q0 + wm + mi * 16 + quad * 4 + r;
    int ccol = c0 + wn + ni * 16 + l16;
    float a2 = 0.f;
    for (int k = 0; k < C; k++) {
      float d = F32[(size_t)qrow * C + k] - F32[(size_t)ccol * C + k];
      a2 = fmaf(d, d, a2);
    }
    if (a2 <= r2) memb |= 1ull << e;
  }
#pragma unroll
  for (int ni = 0; ni < 4; ni++) {
    int cl = wn + ni * 16 + l16;
    unsigned int w0b = 0, w1b = 0;
#pragma unroll
    for (int mi = 0; mi < 4; mi++)
#pragma unroll
      for (int r = 0; r < 4; r++)
        if (memb & (1ull << ((mi << 4) | (ni << 2) | r))) {
          unsigned int bitpos = ((mi & 1) << 4) | (quad << 2) | r;
          if (mi < 2) w0b |= 1u << bitpos;
          else w1b |= 1u << bitpos;
        }
    if (w0b) atomicOr(&tw[cl][(wm >> 5)], w0b);
    if (w1b) atomicOr(&tw[cl][(wm >> 5) + 1], w1b);
  }
  __syncthreads();
  {
    int row = tid >> 1, half = tid & 1;
    int wq = row >> 5, sb = row & 31;
    unsigned int lo = 0, hi = 0;
    for (int j = 0; j < 32; j++) {
      lo |= ((tw[half * 64 + j][wq] >> sb) & 1u) << j;
      hi |= ((tw[half * 64 + 32 + j][wq] >> sb) & 1u) << j;
    }
    mask[(size_t)(q0 + row) * 32 + (ct << 1) + half] =
        ((unsigned long long)hi << 32) | lo;
  }
  if (qt != ct) {
    int row = tid >> 1, word = tid & 1;
    unsigned long long v = (unsigned long long)tw[row][word * 2] |
                           ((unsigned long long)tw[row][word * 2 + 1] << 32);
    mask[(size_t)(c0 + row) * 32 + (qt << 1) + word] = v;
  }
}

// ---------------------------------------------------------------------------
// Ball-query gather v3 — 4 queries/block (one per wave), vectorized loads,
// ZERO __syncthreads. Outputs bit-identical.
// ---------------------------------------------------------------------------
__global__ __launch_bounds__(256) void ball_gather4_f32(
    const unsigned long long* __restrict__ mask,
    const float* __restrict__ H, int CH,
    float* __restrict__ Yf, __hip_bfloat16* __restrict__ Yb,
    __hip_bfloat16* __restrict__ Ylo, float* __restrict__ nrm,
    int ldy, int S)
{
  int blk = blockIdx.x;
  int tid = threadIdx.x;
  int wave = tid >> 6, lane = tid & 63;
  int q = ((blk & 7) << 11) + ((blk >> 3) << 2) + wave;
  int base = q & ~2047;
  __shared__ int idxl[4][64];
  __shared__ float wtab[4][64];
  __shared__ int scount[4];
  if (lane < 32) {
    unsigned long long w = mask[(size_t)q * 32 + lane];
    int cnt = __popcll(w);
    int inc = cnt;
#pragma unroll
    for (int off = 1; off < 32; off <<= 1) {
      int o = __shfl_up(inc, off);
      if (lane >= off) inc += o;
    }
    if (lane == 31) scount[wave] = inc;
    int p = inc - cnt;
    while (w && p < 64) {
      int j = (lane << 6) + __builtin_ctzll(w);
      w &= w - 1;
      idxl[wave][p++] = j;
    }
  }
  int c = scount[wave];  // same-wave write->read: in-order per wave
  {
    int p = lane;
    int cnt = (p < c && p < S) ? ((S - 1 - p) / c + 1) : 0;
    wtab[wave][p] = (float)cnt / (float)S;
  }
  float acc0 = 0.f, acc1 = 0.f;
  int lim = c < S ? c : S;
#pragma unroll 4
  for (int s = 0; s < lim; s++) {
    float wv = wtab[wave][s];
    float2 v = *(const float2*)&H[(size_t)(base + idxl[wave][s]) * CH + lane * 2];
    acc0 += wv * v.x;
    acc1 += wv * v.y;
  }
  int n0 = lane * 2;
  if (Yf) *(float2*)&Yf[(size_t)q * ldy + n0] = make_float2(acc0, acc1);
  if (Yb) {
    Yb[(size_t)q * ldy + n0] = (__hip_bfloat16)acc0;
    Yb[(size_t)q * ldy + n0 + 1] = (__hip_bfloat16)acc1;
  }
  if (Ylo) {
    __hip_bfloat16 h0 = (__hip_bfloat16)acc0, h1 = (__hip_bfloat16)acc1;
    Ylo[(size_t)q * ldy + n0] = (__hip_bfloat16)(acc0 - (float)h0);
    Ylo[(size_t)q * ldy + n0 + 1] = (__hip_bfloat16)(acc1 - (float)h1);
  }
  if (nrm) {
    float nv = acc0 * acc0 + acc1 * acc1;
#pragma unroll
    for (int off = 32; off > 0; off >>= 1) nv += __shfl_down(nv, off);
    if (lane == 0) nrm[q] = nv;
  }
}

__global__ __launch_bounds__(256) void ball_gather4_bf16(
    const unsigned long long* __restrict__ mask,
    const __hip_bfloat16* __restrict__ H, int CH,
    __hip_bfloat16* __restrict__ Yb, int ldy, int S)
{
  int blk = blockIdx.x;
  int tid = threadIdx.x;
  int wave = tid >> 6, lane = tid & 63;
  int q = ((blk & 7) << 11) + ((blk >> 3) << 2) + wave;
  int base = q & ~2047;
  __shared__ int idxl[4][64];
  __shared__ float wtab[4][64];
  __shared__ int scount[4];
  if (lane < 32) {
    unsigned long long w = mask[(size_t)q * 32 + lane];
    int cnt = __popcll(w);
    int inc = cnt;
#pragma unroll
    for (int off = 1; off < 32; off <<= 1) {
      int o = __shfl_up(inc, off);
      if (lane >= off) inc += o;
    }
    if (lane == 31) scount[wave] = inc;
    int p = inc - cnt;
    while (w && p < 64) {
      int j = (lane << 6) + __builtin_ctzll(w);
      w &= w - 1;
      idxl[wave][p++] = j;
    }
  }
  int c = scount[wave];
  {
    int p = lane;
    int cnt = (p < c && p < S) ? ((S - 1 - p) / c + 1) : 0;
    wtab[wave][p] = (float)cnt / (float)S;
  }
  const unsigned short* Hs = (const unsigned short*)H;
  float acc[4] = {0.f, 0.f, 0.f, 0.f};
  int lim = c < S ? c : S;
#pragma unroll 4
  for (int s = 0; s < lim; s++) {
    float wv = wtab[wave][s];
    uint2 v = *(const uint2*)&Hs[(size_t)(base + idxl[wave][s]) * CH + lane * 4];
    acc[0] += wv * __uint_as_float(v.x << 16);
    acc[1] += wv * __uint_as_float(v.x & 0xffff0000u);
    acc[2] += wv * __uint_as_float(v.y << 16);
    acc[3] += wv * __uint_as_float(v.y & 0xffff0000u);
  }
  int n0 = lane * 4;
#pragma unroll
  for (int j = 0; j < 4; j++)
    Yb[(size_t)q * ldy + n0 + j] = (__hip_bfloat16)acc[j];
}

// ---------------------------------------------------------------------------
extern "C" void kernel_launch(void* const* d_in, const int* in_sizes, int n_in,
                              void* d_out, int out_size, void* d_ws,
                              size_t ws_size, hipStream_t stream)
{
  const float* x      = (const float*)d_in[0];
  const float* sa1_w0 = (const float*)d_in[1];
  const float* sa1_b0 = (const float*)d_in[2];
  const float* sa1_w1 = (const float*)d_in[3];
  const float* sa1_b1 = (const float*)d_in[4];
  const float* sa2_w0 = (const float*)d_in[5];
  const float* sa2_b0 = (const float*)d_in[6];
  const float* sa2_w1 = (const float*)d_in[7];
  const float* sa2_b1 = (const float*)d_in[8];
  const float* sa3_w0 = (const float*)d_in[9];
  const float* sa3_b0 = (const float*)d_in[10];
  const float* sa3_w1 = (const float*)d_in[11];
  const float* sa3_b1 = (const float*)d_in[12];
  const float* fp1_w0 = (const float*)d_in[13];
  const float* fp1_b0 = (const float*)d_in[14];
  const float* fp1_w1 = (const float*)d_in[15];
  const float* fp1_b1 = (const float*)d_in[16];
  const float* fp2_w0 = (const float*)d_in[17];
  const float* fp2_b0 = (const float*)d_in[18];
  const float* fp2_w1 = (const float*)d_in[19];
  const float* fp2_b1 = (const float*)d_in[20];
  const float* fc1_w  = (const float*)d_in[21];
  const float* fc1_b  = (const float*)d_in[22];
  const float* fc2_w  = (const float*)d_in[23];
  const float* fc2_b  = (const float*)d_in[24];
  const float* out_w  = (const float*)d_in[25];
  const float* out_b  = (const float*)d_in[26];
  float* out = (float*)d_out;

  const size_t M = M_ROWS;
  float* ws = (float*)d_ws;
  float* G1  = ws + M * 256;
  float* X1  = ws + M * 320;
  float* X2  = ws + M * 384;
  float* H2  = ws + M * 512;
  __hip_bfloat16* H3b16 = (__hip_bfloat16*)(ws + M * 640);
  unsigned long long* MASK = (unsigned long long*)(ws + M * 896);
  __hip_bfloat16* X1b = (__hip_bfloat16*)(ws + M * 960);
  __hip_bfloat16* X2b = (__hip_bfloat16*)(ws + M * 992);
  __hip_bfloat16* TB0 = (__hip_bfloat16*)(ws + M * 1056);
  __hip_bfloat16* TB1 = (__hip_bfloat16*)(ws + M * 1184);
  __hip_bfloat16* TB2 = (__hip_bfloat16*)(ws + M * 1440);
  __hip_bfloat16* G   = (__hip_bfloat16*)(ws + M * 1568);
  __hip_bfloat16* H3b = (__hip_bfloat16*)(ws + M * 2080);
  __hip_bfloat16* WB  = (__hip_bfloat16*)(ws + M * 2208);
  __hip_bfloat16* X1lo = (__hip_bfloat16*)(ws + M * 2240);
  __hip_bfloat16* X2lo = (__hip_bfloat16*)(ws + M * 2272);
  float* nrmX1 = ws + M * 2336;
  float* nrmX2 = ws + M * 2337;
  if (ws_size < (size_t)M * 2340 * sizeof(float)) return;
  __hip_bfloat16* w_sa3_0 = WB;
  __hip_bfloat16* w_sa3_1 = w_sa3_0 + 32768;
  __hip_bfloat16* w_fp1_0 = w_sa3_1 + 65536;
  __hip_bfloat16* w_fp1_1 = w_fp1_0 + 65536;
  __hip_bfloat16* w_fp2_0 = w_fp1_1 + 262144;
  __hip_bfloat16* w_fp2_1 = w_fp2_0 + 16384;
  __hip_bfloat16* w_fc1   = w_fp2_1 + 65536;
  __hip_bfloat16* w_fc2   = w_fc1 + 262144;

  dim3 blk(256);
  TJobs jb;
  const float* srcs[8] = {sa3_w0, sa3_w1, fp1_w0, fp1_w1, fp2_w0, fp2_w1, fc1_w, fc2_w};
  __hip_bfloat16* dsts[8] = {w_sa3_0, w_sa3_1, w_fp1_0, w_fp1_1, w_fp2_0, w_fp2_1, w_fc1, w_fc2};
  int Ks[8] = {128, 256, 128, 512, 64, 256, 1024, 256};
  int Ns[8] = {256, 256, 512, 512, 256, 256, 256, 128};
  int off = 0;
  for (int i = 0; i < 8; i++) {
    jb.W[i] = srcs[i]; jb.Wt[i] = dsts[i];
    jb.K[i] = Ks[i]; jb.N[i] = Ns[i];
    jb.bx[i] = Ns[i] >> 5;
    jb.off[i] = off;
    off += (Ns[i] >> 5) * (Ks[i] >> 5);
  }
  // Prologue: weight transposes + SA1 fused in one dispatch.
  prologue_kernel<<<off + 256, blk, 0, stream>>>(jb, off, x, sa1_w0, sa1_b0,
                                                 sa1_w1, sa1_b1, G1);
  knn_mean4<<<4096, 256, 0, stream>>>(x, G1, X1, X1b, X1lo, nrmX1);
  // SA2 fused + ball64 + gather2 (4 queries/block, float2 loads).
  sa2_fused<<<256, blk, 0, stream>>>(X1, sa2_w0, sa2_b0, sa2_w1, sa2_b1, H2);
  ball_mask_mfma<64><<<dim3(136, 8), blk, 0, stream>>>(X1, X1b, X1lo, nrmX1, MASK, 0.2f * 0.2f);
  ball_gather4_f32<<<4096, blk, 0, stream>>>(MASK, H2, 128, X2, X2b, X2lo, nrmX2, 128, 32);
  // ball128, then the fused layer-1 and layer-2 GEMM triples.
  ball_mask_mfma<128><<<dim3(136, 8), blk, 0, stream>>>(X2, X2b, X2lo, nrmX2, MASK, 0.4f * 0.4f);
  {
    GJobs g1;
    g1.A[0] = (const short*)X2b; g1.W[0] = (const short*)w_sa3_0; g1.bias[0] = sa3_b0;
    g1.Y[0] = TB0; g1.lda[0] = 128; g1.ldw[0] = 128; g1.ldy[0] = 256; g1.N[0] = 256; g1.K[0] = 128;
    g1.A[1] = (const short*)X2b; g1.W[1] = (const short*)w_fp1_0; g1.bias[1] = fp1_b0;
    g1.Y[1] = TB1; g1.lda[1] = 128; g1.ldw[1] = 128; g1.ldy[1] = 512; g1.N[1] = 512; g1.K[1] = 128;
    g1.A[2] = (const short*)X1b; g1.W[2] = (const short*)w_fp2_0; g1.bias[2] = fp2_b0;
    g1.Y[2] = TB2; g1.lda[2] = 64; g1.ldw[2] = 64; g1.ldy[2] = 256; g1.N[2] = 256; g1.K[2] = 64;
    int tot1 = 0;
    for (int i = 0; i < 3; i++) {
      g1.xt[i] = g1.N[i] >> 7;
      g1.off[i] = tot1;
      tot1 += g1.xt[i] * 128;
    }
    gemm_mfma_multi<<<tot1, blk, 0, stream>>>(g1);

    GJobs g2;
    g2.A[0] = (const short*)TB0; g2.W[0] = (const short*)w_sa3_1; g2.bias[0] = sa3_b1;
    g2.Y[0] = H3b16; g2.lda[0] = 256; g2.ldw[0] = 256; g2.ldy[0] = 256; g2.N[0] = 256; g2.K[0] = 256;
    g2.A[1] = (const short*)TB1; g2.W[1] = (const short*)w_fp1_1; g2.bias[1] = fp1_b1;
    g2.Y[1] = G + 256; g2.lda[1] = 512; g2.ldw[1] = 512; g2.ldy[1] = 1024; g2.N[1] = 512; g2.K[1] = 512;
    g2.A[2] = (const short*)TB2; g2.W[2] = (const short*)w_fp2_1; g2.bias[2] = fp2_b1;
    g2.Y[2] = G; g2.lda[2] = 256; g2.ldw[2] = 256; g2.ldy[2] = 1024; g2.N[2] = 256; g2.K[2] = 256;
    int tot2 = 0;
    for (int i = 0; i < 3; i++) {
      g2.xt[i] = g2.N[i] >> 7;
      g2.off[i] = tot2;
      tot2 += g2.xt[i] * 128;
    }
    gemm_mfma_multi<<<tot2, blk, 0, stream>>>(g2);
  }
  // gather3 fills G[768:1024] (4 queries/block, uint2 bf16 loads).
  ball_gather4_bf16<<<4096, blk, 0, stream>>>(MASK, H3b16, 256, G + 768, 1024, 64);
  // Head: fc1 (bf16), then fc2+out fused.
  gemm_mfma<true><<<dim3(2, 128), blk, 0, stream>>>(G, 1024, w_fc1, 1024, fc1_b, H3b, 256, 256, 1024);
  gemm_fc2_out<<<dim3(1, 128), blk, 0, stream>>>(H3b, w_fc2, fc2_b, out_w, out_b, out);
}